// Round 4
// baseline (199.182 us; speedup 1.0000x reference)
//
#include <hip/hip_runtime.h>
#include <math.h>

#define HW 4096
#define CH 128
#define NH 4
#define DH 32

typedef unsigned short u16;
typedef __attribute__((ext_vector_type(8))) short bf16x8;   // 8 bf16 in 4 VGPRs
typedef __attribute__((ext_vector_type(4))) float f32x4;
typedef __attribute__((ext_vector_type(16))) float f32x16;
typedef __attribute__((ext_vector_type(4))) unsigned short u16x4;
typedef __attribute__((ext_vector_type(8))) unsigned short u16x8;

__device__ __forceinline__ u16 f2bf(float f) {
    union { float f; unsigned u; } a; a.f = f;
    unsigned u = a.u;
    unsigned r = u + 0x7FFFu + ((u >> 16) & 1u);   // RNE
    return (u16)(r >> 16);
}

// pack two positive floats to bf16 pair (round-half-up): low = a, high = b
__device__ __forceinline__ unsigned pack2bf(float a, float b) {
    union { float f; unsigned u; } ua, ub; ua.f = a; ub.f = b;
    return __builtin_amdgcn_perm(ub.u + 0x8000u, ua.u + 0x8000u, 0x07060302u);
}

// ---------------- weight fp32->bf16 conversion (every launch) -------------
__global__ __launch_bounds__(256) void convw_kernel(const float* __restrict__ qkv_w,
                                                    const float* __restrict__ proj_w,
                                                    u16* __restrict__ wq, u16* __restrict__ wp) {
    int i = blockIdx.x * 256 + threadIdx.x;
    if (i < 384 * 128) wq[i] = f2bf(qkv_w[i]);
    int j = i - 384 * 128;
    if (j >= 0 && j < 128 * 128) wp[j] = f2bf(proj_w[j]);
}

// ---------------- GroupNorm stats ----------------
__global__ __launch_bounds__(256) void gn_partial_kernel(const float* __restrict__ x,
                                                         float* __restrict__ partials) {
    int t = threadIdx.x;
    const float4* xv = (const float4*)(x + (size_t)blockIdx.x * 4096);
    float s = 0.f, sq = 0.f;
#pragma unroll
    for (int i = 0; i < 4; ++i) {
        float4 v = xv[t + 256 * i];
        s  += v.x + v.y + v.z + v.w;
        sq += v.x * v.x + v.y * v.y + v.z * v.z + v.w * v.w;
    }
#pragma unroll
    for (int off = 32; off > 0; off >>= 1) {
        s  += __shfl_down(s, off, 64);
        sq += __shfl_down(sq, off, 64);
    }
    __shared__ float red[8];
    int wave = t >> 6, lane = t & 63;
    if (lane == 0) { red[wave * 2] = s; red[wave * 2 + 1] = sq; }
    __syncthreads();
    if (t == 0) {
        partials[blockIdx.x * 2]     = red[0] + red[2] + red[4] + red[6];
        partials[blockIdx.x * 2 + 1] = red[1] + red[3] + red[5] + red[7];
    }
}

__global__ __launch_bounds__(256) void gn_finalize_kernel(const float* __restrict__ partials,
                                                          float* __restrict__ stats) {
    int t = threadIdx.x, b = t >> 6, l = t & 63;
    float s  = partials[(b * 128 + l) * 2]     + partials[(b * 128 + 64 + l) * 2];
    float sq = partials[(b * 128 + l) * 2 + 1] + partials[(b * 128 + 64 + l) * 2 + 1];
#pragma unroll
    for (int off = 32; off > 0; off >>= 1) {
        s  += __shfl_down(s, off, 64);
        sq += __shfl_down(sq, off, 64);
    }
    if (l == 0) {
        const float invN = 1.f / (float)(CH * HW);
        float mean = s * invN;
        float var  = sq * invN - mean * mean;
        stats[b * 2]     = mean;
        stats[b * 2 + 1] = rsqrtf(var + 1e-5f);
    }
}

// ---------------- QKV projection via MFMA ----------------
// grid (128 p-tiles of 32, B) x 256. q,k out as [b][h][n][32d] bf16 (k pre-scaled
// by scale*log2e); v as [b][h][32d][m] bf16.
__global__ __launch_bounds__(256) void qkv_mfma_kernel(
    const float* __restrict__ x, const float* __restrict__ gn_w, const float* __restrict__ gn_b,
    const u16* __restrict__ wq, const float* __restrict__ qkv_b, const float* __restrict__ stats,
    u16* __restrict__ qo, u16* __restrict__ ko, u16* __restrict__ vo) {
    __shared__ u16 xt[32 * 136];   // [p][c], pitch 136 u16
    int b = blockIdx.y, p0 = blockIdx.x * 32, t = threadIdx.x;
    float mean = stats[b * 2], rstd = stats[b * 2 + 1];
    const float* xb = x + (size_t)b * CH * HW;
#pragma unroll
    for (int i = 0; i < 4; ++i) {
        int u = t + 256 * i;
        int c = u & 127, p4 = (u >> 7) * 4;
        float4 v = *(const float4*)&xb[(size_t)c * HW + p0 + p4];
        float sc = rstd * gn_w[c], bb = gn_b[c] - mean * sc;
        xt[(p4 + 0) * 136 + c] = f2bf(fmaf(v.x, sc, bb));
        xt[(p4 + 1) * 136 + c] = f2bf(fmaf(v.y, sc, bb));
        xt[(p4 + 2) * 136 + c] = f2bf(fmaf(v.z, sc, bb));
        xt[(p4 + 3) * 136 + c] = f2bf(fmaf(v.w, sc, bb));
    }
    __syncthreads();
    int wave = t >> 6, lane = t & 63, l16 = lane & 15, quad = lane >> 4;
    const float cl2e = 0.17677669529663687f * 1.4426950408889634f;
    f32x4 acc[6][2];
#pragma unroll
    for (int os = 0; os < 6; ++os)
#pragma unroll
        for (int ps = 0; ps < 2; ++ps) acc[os][ps] = f32x4{0.f, 0.f, 0.f, 0.f};
#pragma unroll
    for (int kc = 0; kc < 4; ++kc) {
        bf16x8 bfr[2];
#pragma unroll
        for (int ps = 0; ps < 2; ++ps)
            bfr[ps] = *(const bf16x8*)&xt[(ps * 16 + l16) * 136 + kc * 32 + quad * 8];
#pragma unroll
        for (int os = 0; os < 6; ++os) {
            bf16x8 af = *(const bf16x8*)&wq[(size_t)(wave * 96 + os * 16 + l16) * 128 + kc * 32 + quad * 8];
#pragma unroll
            for (int ps = 0; ps < 2; ++ps)
                acc[os][ps] = __builtin_amdgcn_mfma_f32_16x16x32_bf16(af, bfr[ps], acc[os][ps], 0, 0, 0);
        }
    }
#pragma unroll
    for (int os = 0; os < 6; ++os) {
        int obase = wave * 96 + os * 16 + quad * 4;   // + r
        float4 bias = *(const float4*)&qkv_b[obase];
        int sec = obase >> 7;              // 0=q, 1=k, 2=v  (uniform per (wave,os))
        int oc = obase & 127;
        int h = oc >> 5, d = oc & 31;
        float km = (sec == 1) ? cl2e : 1.f;
#pragma unroll
        for (int ps = 0; ps < 2; ++ps) {
            int p = p0 + ps * 16 + l16;
            float v0 = (acc[os][ps][0] + bias.x) * km;
            float v1 = (acc[os][ps][1] + bias.y) * km;
            float v2 = (acc[os][ps][2] + bias.z) * km;
            float v3 = (acc[os][ps][3] + bias.w) * km;
            if (sec < 2) {
                u16* dst = (sec == 0 ? qo : ko) + ((size_t)(b * NH + h) * HW + p) * DH + d;
                u16x4 pk = {f2bf(v0), f2bf(v1), f2bf(v2), f2bf(v3)};
                *(u16x4*)dst = pk;
            } else {
                u16* dst = vo + ((size_t)(b * NH + h) * DH + d) * HW + p;
                dst[0 * HW] = f2bf(v0);
                dst[1 * HW] = f2bf(v1);
                dst[2 * HW] = f2bf(v2);
                dst[3 * HW] = f2bf(v3);
            }
        }
    }
}

// ---------------- Flash attention, 32x32x16 MFMA, no Ps round-trip --------
// grid (32 n-tiles of 128, NH, B) x 256. Wave w owns n = tile*128 + w*32 + l31.
// S^T[m][n] via A=K,B=Q; P^T reshaped to PV B-operand via shfl_xor(32)+cndmask;
// O^T[d][n] = V*P^T lands directly in the att [c=d*NH+h][n] layout.
// K/V LDS double-buffered, XOR-swizzled 16B granules, one barrier per tile.
__global__ __launch_bounds__(256) void attn_mfma_kernel(
    const u16* __restrict__ q, const u16* __restrict__ k, const u16* __restrict__ v,
    u16* __restrict__ att) {
    __shared__ u16 Ks[2][64 * 32];   // [m][d], granule g' = g ^ (m&3) ^ ((m>>2)&1)
    __shared__ u16 Vs[2][32 * 64];   // [d][m], granule g' = g ^ (d&7)
    int b = blockIdx.z, hh = blockIdx.y, t = threadIdx.x;
    int wave = t >> 6, lane = t & 63, l31 = lane & 31, hf = lane >> 5;
    size_t bh = (size_t)(b * NH + hh);
    const u16* qb = q + bh * HW * DH;
    const u16* kb = k + bh * HW * DH;   // pre-scaled by scale*log2e
    const u16* vb = v + bh * DH * HW;
    int n_g = blockIdx.x * 128 + wave * 32 + l31;

    // loop-invariant Q B-frags: B[col=n][k=d], k = kc*16 + hf*8 + j
    bf16x8 bq0 = *(const bf16x8*)&qb[(size_t)n_g * DH + hf * 8];
    bf16x8 bq1 = *(const bf16x8*)&qb[(size_t)n_g * DH + 16 + hf * 8];

    // staging coords (per thread, 16B K + 16B V per tile)
    int km_ = t >> 2, kg_ = t & 3;
    int kw_idx = km_ * 32 + ((kg_ ^ (km_ & 3) ^ ((km_ >> 2) & 1)) * 8);
    const u16* kgp = kb + km_ * DH + kg_ * 8;
    int vd_ = t >> 3, vg_ = t & 7;
    int vw_idx = vd_ * 64 + ((vg_ ^ (vd_ & 7)) * 8);
    const u16* vgp = vb + (size_t)vd_ * HW + vg_ * 8;

    // per-lane frag-read offsets (swizzled)
    int kswz = (l31 & 3) ^ ((l31 >> 2) & 1);
    int kro[2][2], vro[4];
#pragma unroll
    for (int ms = 0; ms < 2; ++ms)
#pragma unroll
        for (int kc = 0; kc < 2; ++kc)
            kro[ms][kc] = (ms * 32 + l31) * 32 + (((2 * kc + hf) ^ kswz) * 8);
#pragma unroll
    for (int kc = 0; kc < 4; ++kc)
        vro[kc] = l31 * 64 + (((2 * kc + hf) ^ (l31 & 7)) * 8);

    const f32x16 zero16 = {0.f,0.f,0.f,0.f,0.f,0.f,0.f,0.f,0.f,0.f,0.f,0.f,0.f,0.f,0.f,0.f};
    f32x16 accO = zero16;
    float l_part = 0.f;

    // prologue: tile 0 into regs
    bf16x8 kreg = *(const bf16x8*)kgp;
    bf16x8 vreg = *(const bf16x8*)vgp;

    for (int it = 0; it < 64; ++it) {
        int buf = it & 1;
        // stage current tile (vmcnt wait on the prefetch issued last iter)
        *(bf16x8*)&Ks[buf][kw_idx] = kreg;
        *(bf16x8*)&Vs[buf][vw_idx] = vreg;
        __syncthreads();   // visibility; also fences buf reuse (2-buffer proof in journal)
        if (it < 63) {     // issue next-tile loads AFTER barrier so drain doesn't eat them
            kreg = *(const bf16x8*)(kgp + (it + 1) * 64 * DH);
            vreg = *(const bf16x8*)(vgp + (it + 1) * 64);
        }
        // S^T: 2 m-subtiles x (K=32 as 2 chained k16 MFMAs)
        f32x16 s0, s1;
        {
            bf16x8 a00 = *(const bf16x8*)&Ks[buf][kro[0][0]];
            bf16x8 a01 = *(const bf16x8*)&Ks[buf][kro[0][1]];
            s0 = __builtin_amdgcn_mfma_f32_32x32x16_bf16(a00, bq0, zero16, 0, 0, 0);
            s0 = __builtin_amdgcn_mfma_f32_32x32x16_bf16(a01, bq1, s0, 0, 0, 0);
            bf16x8 a10 = *(const bf16x8*)&Ks[buf][kro[1][0]];
            bf16x8 a11 = *(const bf16x8*)&Ks[buf][kro[1][1]];
            s1 = __builtin_amdgcn_mfma_f32_32x32x16_bf16(a10, bq0, zero16, 0, 0, 0);
            s1 = __builtin_amdgcn_mfma_f32_32x32x16_bf16(a11, bq1, s1, 0, 0, 0);
        }
        // exp2 (scale*log2e folded into K; fixed max=0 safe, |s|<<1) + pack + l
        unsigned pk[2][8];
#pragma unroll
        for (int qq = 0; qq < 8; ++qq) {
            float e0 = exp2f(s0[2 * qq]), e1 = exp2f(s0[2 * qq + 1]);
            l_part += e0 + e1;
            pk[0][qq] = pack2bf(e0, e1);
            float f0 = exp2f(s1[2 * qq]), f1 = exp2f(s1[2 * qq + 1]);
            l_part += f0 + f1;
            pk[1][qq] = pack2bf(f0, f1);
        }
        // PV: 4 k16 chunks; B-frag assembled from C-layout pairs via xor-32 shuffle.
        // C-layout: lane(n=l31, hf) holds m = 32ms + 8*(q>>1) + 2*(q&1) + 4*hf + {0,1}.
        // B-frag[kc] needs col n, k=m=kc*16+8*hf+j: pairs q = 4*(kc&1)+2*hf+{0,1}
        // from BOTH lane halves (j<4 from half0, j>=4 from half1).
#pragma unroll
        for (int kc = 0; kc < 4; ++kc) {
            int ms = kc >> 1, Qb = 4 * (kc & 1);
            unsigned a0 = pk[ms][Qb], a1 = pk[ms][Qb + 1];
            unsigned a2 = pk[ms][Qb + 2], a3 = pk[ms][Qb + 3];
            unsigned send0 = hf ? a0 : a2, send1 = hf ? a1 : a3;  // what partner needs
            unsigned self0 = hf ? a2 : a0, self1 = hf ? a3 : a1;  // what I need from me
            unsigned recv0 = (unsigned)__shfl_xor((int)send0, 32, 64);
            unsigned recv1 = (unsigned)__shfl_xor((int)send1, 32, 64);
            union { unsigned u[4]; bf16x8 v; } bu;
            bu.u[0] = hf ? recv0 : self0;   // j=0,1 (from half0)
            bu.u[1] = hf ? recv1 : self1;   // j=2,3
            bu.u[2] = hf ? self0 : recv0;   // j=4,5 (from half1)
            bu.u[3] = hf ? self1 : recv1;   // j=6,7
            bf16x8 av = *(const bf16x8*)&Vs[buf][vro[kc]];
            accO = __builtin_amdgcn_mfma_f32_32x32x16_bf16(av, bu.v, accO, 0, 0, 0);
        }
    }
    // l lives split across the two lane-halves of each column
    l_part += __shfl_xor(l_part, 32, 64);
    float inv = 1.f / l_part;
#pragma unroll
    for (int r = 0; r < 16; ++r) {
        int d = (r & 3) + 8 * (r >> 2) + 4 * hf;
        att[((size_t)b * CH + d * NH + hh) * HW + n_g] = f2bf(accO[r] * inv);
    }
}

// ---------------- Output projection via MFMA + bias + residual ------------
// grid (128 p-tiles of 32, B) x 256
__global__ __launch_bounds__(256) void proj_mfma_kernel(
    const u16* __restrict__ att, const u16* __restrict__ wp, const float* __restrict__ proj_b,
    const float* __restrict__ x, float* __restrict__ out) {
    __shared__ u16 at_t[32 * 136];   // [p][c] pitch 136
    int b = blockIdx.y, p0 = blockIdx.x * 32, t = threadIdx.x;
    const u16* ab = att + (size_t)b * CH * HW;
#pragma unroll
    for (int i = 0; i < 2; ++i) {
        int u = t + 256 * i;
        int c = u & 127, p8 = (u >> 7) * 8;
        u16x8 vv = *(const u16x8*)&ab[(size_t)c * HW + p0 + p8];
#pragma unroll
        for (int j = 0; j < 8; ++j) at_t[(p8 + j) * 136 + c] = vv[j];
    }
    __syncthreads();
    int wave = t >> 6, lane = t & 63, l16 = lane & 15, quad = lane >> 4;
    f32x4 acc[2][2];
#pragma unroll
    for (int os = 0; os < 2; ++os)
#pragma unroll
        for (int ps = 0; ps < 2; ++ps) acc[os][ps] = f32x4{0.f, 0.f, 0.f, 0.f};
#pragma unroll
    for (int kc = 0; kc < 4; ++kc) {
        bf16x8 bfr[2];
#pragma unroll
        for (int ps = 0; ps < 2; ++ps)
            bfr[ps] = *(const bf16x8*)&at_t[(ps * 16 + l16) * 136 + kc * 32 + quad * 8];
#pragma unroll
        for (int os = 0; os < 2; ++os) {
            bf16x8 af = *(const bf16x8*)&wp[(size_t)(wave * 32 + os * 16 + l16) * 128 + kc * 32 + quad * 8];
#pragma unroll
            for (int ps = 0; ps < 2; ++ps)
                acc[os][ps] = __builtin_amdgcn_mfma_f32_16x16x32_bf16(af, bfr[ps], acc[os][ps], 0, 0, 0);
        }
    }
#pragma unroll
    for (int os = 0; os < 2; ++os) {
        int obase = wave * 32 + os * 16 + quad * 4;
#pragma unroll
        for (int ps = 0; ps < 2; ++ps) {
            int p = p0 + ps * 16 + l16;
#pragma unroll
            for (int r = 0; r < 4; ++r) {
                size_t idx = ((size_t)b * CH + obase + r) * HW + p;
                out[idx] = acc[os][ps][r] + proj_b[obase + r] + x[idx];
            }
        }
    }
}

extern "C" void kernel_launch(void* const* d_in, const int* in_sizes, int n_in,
                              void* d_out, int out_size, void* d_ws, size_t ws_size,
                              hipStream_t stream) {
    const float* x      = (const float*)d_in[0];
    const float* gn_w   = (const float*)d_in[1];
    const float* gn_b   = (const float*)d_in[2];
    const float* qkv_w  = (const float*)d_in[3];
    const float* qkv_b  = (const float*)d_in[4];
    const float* proj_w = (const float*)d_in[5];
    const float* proj_b = (const float*)d_in[6];
    float* out = (float*)d_out;

    char* W = (char*)d_ws;
    float* partials = (float*)(W + 0);           // 4 KB
    float* stats    = (float*)(W + 4096);        // 32 B
    u16*   wq       = (u16*)(W + 8192);          // 96 KB
    u16*   wp       = (u16*)(W + 8192 + 98304);  // 32 KB
    u16*   qo       = (u16*)(W + 139264);        // 4 MB each
    u16*   ko       = qo + (size_t)2097152;
    u16*   vo       = ko + (size_t)2097152;
    u16*   att      = vo + (size_t)2097152;      // ends at ~16.9 MB

    hipLaunchKernelGGL(convw_kernel,       dim3(256),       dim3(256), 0, stream,
                       qkv_w, proj_w, wq, wp);
    hipLaunchKernelGGL(gn_partial_kernel,  dim3(512),       dim3(256), 0, stream, x, partials);
    hipLaunchKernelGGL(gn_finalize_kernel, dim3(1),         dim3(256), 0, stream, partials, stats);
    hipLaunchKernelGGL(qkv_mfma_kernel,    dim3(128, 4),    dim3(256), 0, stream,
                       x, gn_w, gn_b, wq, qkv_b, stats, qo, ko, vo);
    hipLaunchKernelGGL(attn_mfma_kernel,   dim3(32, 4, 4),  dim3(256), 0, stream, qo, ko, vo, att);
    hipLaunchKernelGGL(proj_mfma_kernel,   dim3(128, 4),    dim3(256), 0, stream,
                       att, wp, proj_b, x, out);
}

// Round 5
// 171.977 us; speedup vs baseline: 1.1582x; 1.1582x over previous
//
#include <hip/hip_runtime.h>
#include <math.h>

#define HW 4096
#define CH 128
#define NH 4
#define DH 32

typedef unsigned short u16;
typedef __attribute__((ext_vector_type(8))) short bf16x8;   // 8 bf16 in 4 VGPRs
typedef __attribute__((ext_vector_type(4))) float f32x4;
typedef __attribute__((ext_vector_type(16))) float f32x16;
typedef __attribute__((ext_vector_type(4))) unsigned short u16x4;
typedef __attribute__((ext_vector_type(8))) unsigned short u16x8;

// raw v_exp_f32 (args are in [-1,1]; no range fixups needed)
#if __has_builtin(__builtin_amdgcn_exp2f)
#define KFOLD (0.17677669529663687f * 1.4426950408889634f)   // scale * log2(e)
#define FASTEXP(x) __builtin_amdgcn_exp2f(x)
#else
#define KFOLD 0.17677669529663687f                            // scale only
#define FASTEXP(x) __expf(x)
#endif

__device__ __forceinline__ u16 f2bf(float f) {
    union { float f; unsigned u; } a; a.f = f;
    unsigned u = a.u;
    unsigned r = u + 0x7FFFu + ((u >> 16) & 1u);   // RNE
    return (u16)(r >> 16);
}

// pack two positive floats to bf16 pair (round-half-up): low = a, high = b
__device__ __forceinline__ unsigned pack2bf(float a, float b) {
    union { float f; unsigned u; } ua, ub; ua.f = a; ub.f = b;
    return __builtin_amdgcn_perm(ub.u + 0x8000u, ua.u + 0x8000u, 0x07060302u);
}

// ---------------- weight fp32->bf16 conversion (every launch) -------------
__global__ __launch_bounds__(256) void convw_kernel(const float* __restrict__ qkv_w,
                                                    const float* __restrict__ proj_w,
                                                    u16* __restrict__ wq, u16* __restrict__ wp) {
    int i = blockIdx.x * 256 + threadIdx.x;
    if (i < 384 * 128) wq[i] = f2bf(qkv_w[i]);
    int j = i - 384 * 128;
    if (j >= 0 && j < 128 * 128) wp[j] = f2bf(proj_w[j]);
}

// ---------------- GroupNorm stats ----------------
__global__ __launch_bounds__(256) void gn_partial_kernel(const float* __restrict__ x,
                                                         float* __restrict__ partials) {
    int t = threadIdx.x;
    const float4* xv = (const float4*)(x + (size_t)blockIdx.x * 4096);
    float s = 0.f, sq = 0.f;
#pragma unroll
    for (int i = 0; i < 4; ++i) {
        float4 v = xv[t + 256 * i];
        s  += v.x + v.y + v.z + v.w;
        sq += v.x * v.x + v.y * v.y + v.z * v.z + v.w * v.w;
    }
#pragma unroll
    for (int off = 32; off > 0; off >>= 1) {
        s  += __shfl_down(s, off, 64);
        sq += __shfl_down(sq, off, 64);
    }
    __shared__ float red[8];
    int wave = t >> 6, lane = t & 63;
    if (lane == 0) { red[wave * 2] = s; red[wave * 2 + 1] = sq; }
    __syncthreads();
    if (t == 0) {
        partials[blockIdx.x * 2]     = red[0] + red[2] + red[4] + red[6];
        partials[blockIdx.x * 2 + 1] = red[1] + red[3] + red[5] + red[7];
    }
}

__global__ __launch_bounds__(256) void gn_finalize_kernel(const float* __restrict__ partials,
                                                          float* __restrict__ stats) {
    int t = threadIdx.x, b = t >> 6, l = t & 63;
    float s  = partials[(b * 128 + l) * 2]     + partials[(b * 128 + 64 + l) * 2];
    float sq = partials[(b * 128 + l) * 2 + 1] + partials[(b * 128 + 64 + l) * 2 + 1];
#pragma unroll
    for (int off = 32; off > 0; off >>= 1) {
        s  += __shfl_down(s, off, 64);
        sq += __shfl_down(sq, off, 64);
    }
    if (l == 0) {
        const float invN = 1.f / (float)(CH * HW);
        float mean = s * invN;
        float var  = sq * invN - mean * mean;
        stats[b * 2]     = mean;
        stats[b * 2 + 1] = rsqrtf(var + 1e-5f);
    }
}

// ---------------- QKV projection via MFMA ----------------
// grid (128 p-tiles of 32, B) x 256. q,k out as [b][h][n][32d] bf16 (k pre-scaled
// by KFOLD); v as [b][h][32d][m] bf16.
__global__ __launch_bounds__(256) void qkv_mfma_kernel(
    const float* __restrict__ x, const float* __restrict__ gn_w, const float* __restrict__ gn_b,
    const u16* __restrict__ wq, const float* __restrict__ qkv_b, const float* __restrict__ stats,
    u16* __restrict__ qo, u16* __restrict__ ko, u16* __restrict__ vo) {
    __shared__ u16 xt[32 * 136];   // [p][c], pitch 136 u16
    int b = blockIdx.y, p0 = blockIdx.x * 32, t = threadIdx.x;
    float mean = stats[b * 2], rstd = stats[b * 2 + 1];
    const float* xb = x + (size_t)b * CH * HW;
#pragma unroll
    for (int i = 0; i < 4; ++i) {
        int u = t + 256 * i;
        int c = u & 127, p4 = (u >> 7) * 4;
        float4 v = *(const float4*)&xb[(size_t)c * HW + p0 + p4];
        float sc = rstd * gn_w[c], bb = gn_b[c] - mean * sc;
        xt[(p4 + 0) * 136 + c] = f2bf(fmaf(v.x, sc, bb));
        xt[(p4 + 1) * 136 + c] = f2bf(fmaf(v.y, sc, bb));
        xt[(p4 + 2) * 136 + c] = f2bf(fmaf(v.z, sc, bb));
        xt[(p4 + 3) * 136 + c] = f2bf(fmaf(v.w, sc, bb));
    }
    __syncthreads();
    int wave = t >> 6, lane = t & 63, l16 = lane & 15, quad = lane >> 4;
    f32x4 acc[6][2];
#pragma unroll
    for (int os = 0; os < 6; ++os)
#pragma unroll
        for (int ps = 0; ps < 2; ++ps) acc[os][ps] = f32x4{0.f, 0.f, 0.f, 0.f};
#pragma unroll
    for (int kc = 0; kc < 4; ++kc) {
        bf16x8 bfr[2];
#pragma unroll
        for (int ps = 0; ps < 2; ++ps)
            bfr[ps] = *(const bf16x8*)&xt[(ps * 16 + l16) * 136 + kc * 32 + quad * 8];
#pragma unroll
        for (int os = 0; os < 6; ++os) {
            bf16x8 af = *(const bf16x8*)&wq[(size_t)(wave * 96 + os * 16 + l16) * 128 + kc * 32 + quad * 8];
#pragma unroll
            for (int ps = 0; ps < 2; ++ps)
                acc[os][ps] = __builtin_amdgcn_mfma_f32_16x16x32_bf16(af, bfr[ps], acc[os][ps], 0, 0, 0);
        }
    }
#pragma unroll
    for (int os = 0; os < 6; ++os) {
        int obase = wave * 96 + os * 16 + quad * 4;   // + r
        float4 bias = *(const float4*)&qkv_b[obase];
        int sec = obase >> 7;              // 0=q, 1=k, 2=v  (uniform per (wave,os))
        int oc = obase & 127;
        int h = oc >> 5, d = oc & 31;
        float km = (sec == 1) ? KFOLD : 1.f;
#pragma unroll
        for (int ps = 0; ps < 2; ++ps) {
            int p = p0 + ps * 16 + l16;
            float v0 = (acc[os][ps][0] + bias.x) * km;
            float v1 = (acc[os][ps][1] + bias.y) * km;
            float v2 = (acc[os][ps][2] + bias.z) * km;
            float v3 = (acc[os][ps][3] + bias.w) * km;
            if (sec < 2) {
                u16* dst = (sec == 0 ? qo : ko) + ((size_t)(b * NH + h) * HW + p) * DH + d;
                u16x4 pk = {f2bf(v0), f2bf(v1), f2bf(v2), f2bf(v3)};
                *(u16x4*)dst = pk;
            } else {
                u16* dst = vo + ((size_t)(b * NH + h) * DH + d) * HW + p;
                dst[0 * HW] = f2bf(v0);
                dst[1 * HW] = f2bf(v1);
                dst[2 * HW] = f2bf(v2);
                dst[3 * HW] = f2bf(v3);
            }
        }
    }
}

// ---------------- Flash attention, 32x32x16 MFMA, m-split decoding --------
// grid (32 n-tiles of 128, 2 m-parts, 16 bh) x 256. Fixed-max softmax makes
// numerator/denominator plain sums over m -> m-parts are additive; each part
// writes partial O (fp32, [c][n] layout) + partial l; combine kernel divides.
__global__ __launch_bounds__(256) void attn_mfma_kernel(
    const u16* __restrict__ q, const u16* __restrict__ k, const u16* __restrict__ v,
    float* __restrict__ Op0, float* __restrict__ Op1,
    float* __restrict__ lp0, float* __restrict__ lp1) {
    __shared__ u16 Ks[2][64 * 32];   // [m][d], granule g' = g ^ (m&3) ^ ((m>>2)&1)
    __shared__ u16 Vs[2][32 * 64];   // [d][m], granule g' = g ^ (d&7)
    int bh = blockIdx.z, mpart = blockIdx.y, t = threadIdx.x;
    int b = bh >> 2, hh = bh & 3;
    int wave = t >> 6, lane = t & 63, l31 = lane & 31, hf = lane >> 5;
    const u16* qb = q + (size_t)bh * HW * DH;
    const u16* kb = k + (size_t)bh * HW * DH;   // pre-scaled by KFOLD
    const u16* vb = v + (size_t)bh * DH * HW;
    int n_g = blockIdx.x * 128 + wave * 32 + l31;
    int m_base = mpart * 2048;

    // loop-invariant Q B-frags: B[col=n][k=d], k = kc*16 + hf*8 + j
    bf16x8 bq0 = *(const bf16x8*)&qb[(size_t)n_g * DH + hf * 8];
    bf16x8 bq1 = *(const bf16x8*)&qb[(size_t)n_g * DH + 16 + hf * 8];

    // staging coords (per thread, 16B K + 16B V per tile)
    int km_ = t >> 2, kg_ = t & 3;
    int kw_idx = km_ * 32 + ((kg_ ^ (km_ & 3) ^ ((km_ >> 2) & 1)) * 8);
    const u16* kgp = kb + (size_t)(m_base + km_) * DH + kg_ * 8;
    int vd_ = t >> 3, vg_ = t & 7;
    int vw_idx = vd_ * 64 + ((vg_ ^ (vd_ & 7)) * 8);
    const u16* vgp = vb + (size_t)vd_ * HW + m_base + vg_ * 8;

    // per-lane frag-read offsets (swizzled)
    int kswz = (l31 & 3) ^ ((l31 >> 2) & 1);
    int kro[2][2], vro[4];
#pragma unroll
    for (int ms = 0; ms < 2; ++ms)
#pragma unroll
        for (int kc = 0; kc < 2; ++kc)
            kro[ms][kc] = (ms * 32 + l31) * 32 + (((2 * kc + hf) ^ kswz) * 8);
#pragma unroll
    for (int kc = 0; kc < 4; ++kc)
        vro[kc] = l31 * 64 + (((2 * kc + hf) ^ (l31 & 7)) * 8);

    const f32x16 zero16 = {0.f,0.f,0.f,0.f,0.f,0.f,0.f,0.f,0.f,0.f,0.f,0.f,0.f,0.f,0.f,0.f};
    f32x16 accO = zero16;
    float l_part = 0.f;

    // prologue: first tile of this m-part into regs
    bf16x8 kreg = *(const bf16x8*)kgp;
    bf16x8 vreg = *(const bf16x8*)vgp;

    for (int it = 0; it < 32; ++it) {
        int buf = it & 1;
        *(bf16x8*)&Ks[buf][kw_idx] = kreg;
        *(bf16x8*)&Vs[buf][vw_idx] = vreg;
        __syncthreads();
        if (it < 31) {     // issue next-tile loads AFTER barrier so drain doesn't eat them
            kreg = *(const bf16x8*)(kgp + (size_t)(it + 1) * 64 * DH);
            vreg = *(const bf16x8*)(vgp + (it + 1) * 64);
        }
        // S^T: 2 m-subtiles x (K=32 as 2 chained k16 MFMAs)
        f32x16 s0, s1;
        {
            bf16x8 a00 = *(const bf16x8*)&Ks[buf][kro[0][0]];
            bf16x8 a01 = *(const bf16x8*)&Ks[buf][kro[0][1]];
            s0 = __builtin_amdgcn_mfma_f32_32x32x16_bf16(a00, bq0, zero16, 0, 0, 0);
            s0 = __builtin_amdgcn_mfma_f32_32x32x16_bf16(a01, bq1, s0, 0, 0, 0);
            bf16x8 a10 = *(const bf16x8*)&Ks[buf][kro[1][0]];
            bf16x8 a11 = *(const bf16x8*)&Ks[buf][kro[1][1]];
            s1 = __builtin_amdgcn_mfma_f32_32x32x16_bf16(a10, bq0, zero16, 0, 0, 0);
            s1 = __builtin_amdgcn_mfma_f32_32x32x16_bf16(a11, bq1, s1, 0, 0, 0);
        }
        // p = FASTEXP(s): single v_exp_f32 (KFOLD folded into K; fixed max=0, |s|<<1)
        unsigned pk[2][8];
#pragma unroll
        for (int qq = 0; qq < 8; ++qq) {
            float e0 = FASTEXP(s0[2 * qq]), e1 = FASTEXP(s0[2 * qq + 1]);
            l_part += e0 + e1;
            pk[0][qq] = pack2bf(e0, e1);
            float f0 = FASTEXP(s1[2 * qq]), f1 = FASTEXP(s1[2 * qq + 1]);
            l_part += f0 + f1;
            pk[1][qq] = pack2bf(f0, f1);
        }
        // PV: 4 k16 chunks; B-frag assembled from C-layout pairs via xor-32 shuffle.
#pragma unroll
        for (int kc = 0; kc < 4; ++kc) {
            int ms = kc >> 1, Qb = 4 * (kc & 1);
            unsigned a0 = pk[ms][Qb], a1 = pk[ms][Qb + 1];
            unsigned a2 = pk[ms][Qb + 2], a3 = pk[ms][Qb + 3];
            unsigned send0 = hf ? a0 : a2, send1 = hf ? a1 : a3;
            unsigned self0 = hf ? a2 : a0, self1 = hf ? a3 : a1;
            unsigned recv0 = (unsigned)__shfl_xor((int)send0, 32, 64);
            unsigned recv1 = (unsigned)__shfl_xor((int)send1, 32, 64);
            union { unsigned u[4]; bf16x8 v; } bu;
            bu.u[0] = hf ? recv0 : self0;
            bu.u[1] = hf ? recv1 : self1;
            bu.u[2] = hf ? self0 : recv0;
            bu.u[3] = hf ? self1 : recv1;
            bf16x8 av = *(const bf16x8*)&Vs[buf][vro[kc]];
            accO = __builtin_amdgcn_mfma_f32_32x32x16_bf16(av, bu.v, accO, 0, 0, 0);
        }
    }
    // partial l: combine the two lane-halves of each column
    l_part += __shfl_xor(l_part, 32, 64);
    float* Op = mpart ? Op1 : Op0;
#pragma unroll
    for (int r = 0; r < 16; ++r) {
        int d = (r & 3) + 8 * (r >> 2) + 4 * hf;
        Op[((size_t)b * CH + d * NH + hh) * HW + n_g] = accO[r];
    }
    if (hf == 0) (mpart ? lp1 : lp0)[(size_t)bh * HW + n_g] = l_part;
}

// ---------------- combine partial O / l -> bf16 att ----------------
// grid 2048 x 256; thread = one float4 along n of one (b,c) row
__global__ __launch_bounds__(256) void attn_combine_kernel(
    const float* __restrict__ Op0, const float* __restrict__ Op1,
    const float* __restrict__ lp0, const float* __restrict__ lp1,
    u16* __restrict__ att) {
    int idx = blockIdx.x * 256 + threadIdx.x;   // 524288 total
    int n4 = idx & 1023;                        // float4 index in n
    int bc = idx >> 10;                         // b*128 + c
    int c = bc & 127, b = bc >> 7;
    int h = c & 3;
    int bh = b * NH + h;
    float4 o0 = ((const float4*)Op0)[idx];
    float4 o1 = ((const float4*)Op1)[idx];
    float4 a0 = ((const float4*)lp0)[bh * 1024 + n4];
    float4 a1 = ((const float4*)lp1)[bh * 1024 + n4];
    u16x4 pk;
    pk[0] = f2bf((o0.x + o1.x) / (a0.x + a1.x));
    pk[1] = f2bf((o0.y + o1.y) / (a0.y + a1.y));
    pk[2] = f2bf((o0.z + o1.z) / (a0.z + a1.z));
    pk[3] = f2bf((o0.w + o1.w) / (a0.w + a1.w));
    *(u16x4*)&att[(size_t)idx * 4] = pk;
}

// ---------------- Output projection via MFMA + bias + residual ------------
// grid (128 p-tiles of 32, B) x 256
__global__ __launch_bounds__(256) void proj_mfma_kernel(
    const u16* __restrict__ att, const u16* __restrict__ wp, const float* __restrict__ proj_b,
    const float* __restrict__ x, float* __restrict__ out) {
    __shared__ u16 at_t[32 * 136];   // [p][c] pitch 136
    int b = blockIdx.y, p0 = blockIdx.x * 32, t = threadIdx.x;
    const u16* ab = att + (size_t)b * CH * HW;
#pragma unroll
    for (int i = 0; i < 2; ++i) {
        int u = t + 256 * i;
        int c = u & 127, p8 = (u >> 7) * 8;
        u16x8 vv = *(const u16x8*)&ab[(size_t)c * HW + p0 + p8];
#pragma unroll
        for (int j = 0; j < 8; ++j) at_t[(p8 + j) * 136 + c] = vv[j];
    }
    __syncthreads();
    int wave = t >> 6, lane = t & 63, l16 = lane & 15, quad = lane >> 4;
    f32x4 acc[2][2];
#pragma unroll
    for (int os = 0; os < 2; ++os)
#pragma unroll
        for (int ps = 0; ps < 2; ++ps) acc[os][ps] = f32x4{0.f, 0.f, 0.f, 0.f};
#pragma unroll
    for (int kc = 0; kc < 4; ++kc) {
        bf16x8 bfr[2];
#pragma unroll
        for (int ps = 0; ps < 2; ++ps)
            bfr[ps] = *(const bf16x8*)&at_t[(ps * 16 + l16) * 136 + kc * 32 + quad * 8];
#pragma unroll
        for (int os = 0; os < 2; ++os) {
            bf16x8 af = *(const bf16x8*)&wp[(size_t)(wave * 32 + os * 16 + l16) * 128 + kc * 32 + quad * 8];
#pragma unroll
            for (int ps = 0; ps < 2; ++ps)
                acc[os][ps] = __builtin_amdgcn_mfma_f32_16x16x32_bf16(af, bfr[ps], acc[os][ps], 0, 0, 0);
        }
    }
#pragma unroll
    for (int os = 0; os < 2; ++os) {
        int obase = wave * 32 + os * 16 + quad * 4;
#pragma unroll
        for (int ps = 0; ps < 2; ++ps) {
            int p = p0 + ps * 16 + l16;
#pragma unroll
            for (int r = 0; r < 4; ++r) {
                size_t idx = ((size_t)b * CH + obase + r) * HW + p;
                out[idx] = acc[os][ps][r] + proj_b[obase + r] + x[idx];
            }
        }
    }
}

extern "C" void kernel_launch(void* const* d_in, const int* in_sizes, int n_in,
                              void* d_out, int out_size, void* d_ws, size_t ws_size,
                              hipStream_t stream) {
    const float* x      = (const float*)d_in[0];
    const float* gn_w   = (const float*)d_in[1];
    const float* gn_b   = (const float*)d_in[2];
    const float* qkv_w  = (const float*)d_in[3];
    const float* qkv_b  = (const float*)d_in[4];
    const float* proj_w = (const float*)d_in[5];
    const float* proj_b = (const float*)d_in[6];
    float* out = (float*)d_out;

    char* W = (char*)d_ws;
    float* partials = (float*)(W + 0);           // 4 KB
    float* stats    = (float*)(W + 4096);        // 32 B
    u16*   wq       = (u16*)(W + 8192);          // 96 KB
    u16*   wp       = (u16*)(W + 8192 + 98304);  // 32 KB
    u16*   qo       = (u16*)(W + 139264);        // 4 MB each
    u16*   ko       = qo + (size_t)2097152;
    u16*   vo       = ko + (size_t)2097152;
    u16*   att      = vo + (size_t)2097152;
    char*  W2       = (char*)(att + (size_t)2097152);   // 16916480
    float* Op0      = (float*)W2;                        // 8 MB
    float* Op1      = (float*)(W2 + 8388608);            // 8 MB
    float* lp0      = (float*)(W2 + 16777216);           // 256 KB
    float* lp1      = (float*)(W2 + 17039360);           // 256 KB -> total ~34.2 MB

    hipLaunchKernelGGL(convw_kernel,        dim3(256),       dim3(256), 0, stream,
                       qkv_w, proj_w, wq, wp);
    hipLaunchKernelGGL(gn_partial_kernel,   dim3(512),       dim3(256), 0, stream, x, partials);
    hipLaunchKernelGGL(gn_finalize_kernel,  dim3(1),         dim3(256), 0, stream, partials, stats);
    hipLaunchKernelGGL(qkv_mfma_kernel,     dim3(128, 4),    dim3(256), 0, stream,
                       x, gn_w, gn_b, wq, qkv_b, stats, qo, ko, vo);
    hipLaunchKernelGGL(attn_mfma_kernel,    dim3(32, 2, 16), dim3(256), 0, stream,
                       qo, ko, vo, Op0, Op1, lp0, lp1);
    hipLaunchKernelGGL(attn_combine_kernel, dim3(2048),      dim3(256), 0, stream,
                       Op0, Op1, lp0, lp1, att);
    hipLaunchKernelGGL(proj_mfma_kernel,    dim3(128, 4),    dim3(256), 0, stream,
                       att, wp, proj_b, x, out);
}

// Round 6
// 163.205 us; speedup vs baseline: 1.2204x; 1.0537x over previous
//
#include <hip/hip_runtime.h>
#include <math.h>

#define HW 4096
#define CH 128
#define NH 4
#define DH 32

typedef unsigned short u16;
typedef __attribute__((ext_vector_type(8))) short bf16x8;   // 8 bf16 in 4 VGPRs
typedef __attribute__((ext_vector_type(4))) float f32x4;
typedef __attribute__((ext_vector_type(16))) float f32x16;
typedef __attribute__((ext_vector_type(4))) unsigned short u16x4;
typedef __attribute__((ext_vector_type(8))) unsigned short u16x8;

// raw v_exp_f32 (args are in [-1,1]; no range fixups needed)
#if __has_builtin(__builtin_amdgcn_exp2f)
#define KFOLD (0.17677669529663687f * 1.4426950408889634f)   // scale * log2(e)
#define FASTEXP(x) __builtin_amdgcn_exp2f(x)
#else
#define KFOLD 0.17677669529663687f                            // scale only
#define FASTEXP(x) __expf(x)
#endif

#if __has_builtin(__builtin_amdgcn_rcpf)
#define RCPF(x) __builtin_amdgcn_rcpf(x)
#else
#define RCPF(x) (1.f / (x))
#endif

__device__ __forceinline__ u16 f2bf(float f) {
    union { float f; unsigned u; } a; a.f = f;
    unsigned u = a.u;
    unsigned r = u + 0x7FFFu + ((u >> 16) & 1u);   // RNE
    return (u16)(r >> 16);
}
__device__ __forceinline__ float bf2f(u16 u) {
    union { unsigned u; float f; } a; a.u = ((unsigned)u) << 16;
    return a.f;
}
// pack two positive floats to bf16 pair by TRUNCATION (1 v_perm): low=a, high=b
__device__ __forceinline__ unsigned pack2bf_t(float a, float b) {
    union { float f; unsigned u; } ua, ub; ua.f = a; ub.f = b;
    return __builtin_amdgcn_perm(ub.u, ua.u, 0x07060302u);
}

// ---------------- Fused: weight bf16 conversion + GroupNorm partials ------
// blocks 0..511: gn partials (128 chunks x 4 batches); blocks 512..767: convw
__global__ __launch_bounds__(256) void prep_kernel(
    const float* __restrict__ x, float* __restrict__ partials,
    const float* __restrict__ qkv_w, const float* __restrict__ proj_w,
    u16* __restrict__ wq, u16* __restrict__ wp) {
    int blk = blockIdx.x, t = threadIdx.x;
    if (blk < 512) {
        const float4* xv = (const float4*)(x + (size_t)blk * 4096);
        float s = 0.f, sq = 0.f;
#pragma unroll
        for (int i = 0; i < 4; ++i) {
            float4 v = xv[t + 256 * i];
            s  += v.x + v.y + v.z + v.w;
            sq += v.x * v.x + v.y * v.y + v.z * v.z + v.w * v.w;
        }
#pragma unroll
        for (int off = 32; off > 0; off >>= 1) {
            s  += __shfl_down(s, off, 64);
            sq += __shfl_down(sq, off, 64);
        }
        __shared__ float red[8];
        int wave = t >> 6, lane = t & 63;
        if (lane == 0) { red[wave * 2] = s; red[wave * 2 + 1] = sq; }
        __syncthreads();
        if (t == 0) {
            partials[blk * 2]     = red[0] + red[2] + red[4] + red[6];
            partials[blk * 2 + 1] = red[1] + red[3] + red[5] + red[7];
        }
    } else {
        int i = (blk - 512) * 256 + t;              // [0, 65536)
        if (i < 49152) wq[i] = f2bf(qkv_w[i]);
        else           wp[i - 49152] = f2bf(proj_w[i - 49152]);
    }
}

// ---------------- QKV projection via MFMA (inline GN finalize) ------------
// grid (128 p-tiles of 32, B) x 256. q,k out as [b][h][n][32d] bf16 (k pre-scaled
// by KFOLD); v as [b][h][32d][m] bf16 with m-columns PERMUTED by swap of m-bits
// 2<->3 (so attn's PV B-operand is a direct register reinterpret of P).
__global__ __launch_bounds__(256) void qkv_mfma_kernel(
    const float* __restrict__ x, const float* __restrict__ gn_w, const float* __restrict__ gn_b,
    const u16* __restrict__ wq, const float* __restrict__ qkv_b, const float* __restrict__ partials,
    u16* __restrict__ qo, u16* __restrict__ ko, u16* __restrict__ vo) {
    __shared__ u16 xt[32 * 136];   // [p][c], pitch 136 u16
    __shared__ float sstats[2];
    int b = blockIdx.y, p0 = blockIdx.x * 32, t = threadIdx.x;
    const float* xb = x + (size_t)b * CH * HW;
    float4 xv[4]; int cc[4], pp[4];
#pragma unroll
    for (int i = 0; i < 4; ++i) {
        int u = t + 256 * i;
        cc[i] = u & 127; pp[i] = (u >> 7) * 4;
        xv[i] = *(const float4*)&xb[(size_t)cc[i] * HW + p0 + pp[i]];
    }
    if (t < 64) {   // per-block redundant finalize (2 KB L2 read, one wave)
        float s  = partials[(b * 128 + t) * 2]     + partials[(b * 128 + 64 + t) * 2];
        float sq = partials[(b * 128 + t) * 2 + 1] + partials[(b * 128 + 64 + t) * 2 + 1];
#pragma unroll
        for (int off = 32; off > 0; off >>= 1) {
            s  += __shfl_down(s, off, 64);
            sq += __shfl_down(sq, off, 64);
        }
        if (t == 0) {
            const float invN = 1.f / (float)(CH * HW);
            float mean = s * invN;
            float var  = sq * invN - mean * mean;
            sstats[0] = mean;
            sstats[1] = rsqrtf(var + 1e-5f);
        }
    }
    __syncthreads();
    float mean = sstats[0], rstd = sstats[1];
#pragma unroll
    for (int i = 0; i < 4; ++i) {
        float sc = rstd * gn_w[cc[i]], bb = gn_b[cc[i]] - mean * sc;
        xt[(pp[i] + 0) * 136 + cc[i]] = f2bf(fmaf(xv[i].x, sc, bb));
        xt[(pp[i] + 1) * 136 + cc[i]] = f2bf(fmaf(xv[i].y, sc, bb));
        xt[(pp[i] + 2) * 136 + cc[i]] = f2bf(fmaf(xv[i].z, sc, bb));
        xt[(pp[i] + 3) * 136 + cc[i]] = f2bf(fmaf(xv[i].w, sc, bb));
    }
    __syncthreads();
    int wave = t >> 6, lane = t & 63, l16 = lane & 15, quad = lane >> 4;
    f32x4 acc[6][2];
#pragma unroll
    for (int os = 0; os < 6; ++os)
#pragma unroll
        for (int ps = 0; ps < 2; ++ps) acc[os][ps] = f32x4{0.f, 0.f, 0.f, 0.f};
#pragma unroll
    for (int kc = 0; kc < 4; ++kc) {
        bf16x8 bfr[2];
#pragma unroll
        for (int ps = 0; ps < 2; ++ps)
            bfr[ps] = *(const bf16x8*)&xt[(ps * 16 + l16) * 136 + kc * 32 + quad * 8];
#pragma unroll
        for (int os = 0; os < 6; ++os) {
            bf16x8 af = *(const bf16x8*)&wq[(size_t)(wave * 96 + os * 16 + l16) * 128 + kc * 32 + quad * 8];
#pragma unroll
            for (int ps = 0; ps < 2; ++ps)
                acc[os][ps] = __builtin_amdgcn_mfma_f32_16x16x32_bf16(af, bfr[ps], acc[os][ps], 0, 0, 0);
        }
    }
    int l16p = (l16 & 3) | ((l16 & 4) << 1) | ((l16 & 8) >> 1);   // swap bits 2,3
#pragma unroll
    for (int os = 0; os < 6; ++os) {
        int obase = wave * 96 + os * 16 + quad * 4;   // + r
        float4 bias = *(const float4*)&qkv_b[obase];
        int sec = obase >> 7;              // 0=q, 1=k, 2=v  (uniform per (wave,os))
        int oc = obase & 127;
        int h = oc >> 5, d = oc & 31;
        float km = (sec == 1) ? KFOLD : 1.f;
#pragma unroll
        for (int ps = 0; ps < 2; ++ps) {
            float v0 = (acc[os][ps][0] + bias.x) * km;
            float v1 = (acc[os][ps][1] + bias.y) * km;
            float v2 = (acc[os][ps][2] + bias.z) * km;
            float v3 = (acc[os][ps][3] + bias.w) * km;
            if (sec < 2) {
                int p = p0 + ps * 16 + l16;
                u16* dst = (sec == 0 ? qo : ko) + ((size_t)(b * NH + h) * HW + p) * DH + d;
                u16x4 pk = {f2bf(v0), f2bf(v1), f2bf(v2), f2bf(v3)};
                *(u16x4*)dst = pk;
            } else {
                int pv = p0 + ps * 16 + l16p;          // permuted m-column
                u16* dst = vo + ((size_t)(b * NH + h) * DH + d) * HW + pv;
                dst[0 * HW] = f2bf(v0);
                dst[1 * HW] = f2bf(v1);
                dst[2 * HW] = f2bf(v2);
                dst[3 * HW] = f2bf(v3);
            }
        }
    }
}

// ---------------- Flash attention, 32x32x16 MFMA, 4-way m-split -----------
// grid (32 n-tiles of 128, 4 m-parts, 16 bh) x 256. Fixed-max softmax ->
// partial numerator/denominator are additive. V m-permuted at QKV time, so
// the PV B-operand is the packed P registers directly (no cross-lane ops).
__global__ __launch_bounds__(256) void attn_mfma_kernel(
    const u16* __restrict__ q, const u16* __restrict__ k, const u16* __restrict__ v,
    u16* __restrict__ Op, float* __restrict__ lp) {
    __shared__ u16 Ks[2][64 * 32];   // [m][d], granule g' = g ^ (m&3) ^ ((m>>2)&1)
    __shared__ u16 Vs[2][32 * 64];   // [d][m_perm], granule g' = g ^ (d&7)
    int bh = blockIdx.z, mpart = blockIdx.y, t = threadIdx.x;
    int b = bh >> 2, hh = bh & 3;
    int wave = t >> 6, lane = t & 63, l31 = lane & 31, hf = lane >> 5;
    const u16* qb = q + (size_t)bh * HW * DH;
    const u16* kb = k + (size_t)bh * HW * DH;   // pre-scaled by KFOLD
    const u16* vb = v + (size_t)bh * DH * HW;
    int n_g = blockIdx.x * 128 + wave * 32 + l31;
    int m_base = mpart * 1024;

    // loop-invariant Q B-frags: B[col=n][k=d], k = kc*16 + hf*8 + j
    bf16x8 bq0 = *(const bf16x8*)&qb[(size_t)n_g * DH + hf * 8];
    bf16x8 bq1 = *(const bf16x8*)&qb[(size_t)n_g * DH + 16 + hf * 8];

    // staging coords (per thread, 16B K + 16B V per tile)
    int km_ = t >> 2, kg_ = t & 3;
    int kw_idx = km_ * 32 + ((kg_ ^ (km_ & 3) ^ ((km_ >> 2) & 1)) * 8);
    const u16* kgp = kb + (size_t)(m_base + km_) * DH + kg_ * 8;
    int vd_ = t >> 3, vg_ = t & 7;
    int vw_idx = vd_ * 64 + ((vg_ ^ (vd_ & 7)) * 8);
    const u16* vgp = vb + (size_t)vd_ * HW + m_base + vg_ * 8;

    // per-lane frag-read offsets (swizzled)
    int kswz = (l31 & 3) ^ ((l31 >> 2) & 1);
    int kro[2][2], vro[4];
#pragma unroll
    for (int ms = 0; ms < 2; ++ms)
#pragma unroll
        for (int kc = 0; kc < 2; ++kc)
            kro[ms][kc] = (ms * 32 + l31) * 32 + (((2 * kc + hf) ^ kswz) * 8);
#pragma unroll
    for (int kc = 0; kc < 4; ++kc)
        vro[kc] = l31 * 64 + (((2 * kc + hf) ^ (l31 & 7)) * 8);

    const f32x16 zero16 = {0.f,0.f,0.f,0.f,0.f,0.f,0.f,0.f,0.f,0.f,0.f,0.f,0.f,0.f,0.f,0.f};
    f32x16 accO = zero16;
    float l_part = 0.f;

    // prologue: first tile of this m-part into regs
    bf16x8 kreg = *(const bf16x8*)kgp;
    bf16x8 vreg = *(const bf16x8*)vgp;

    for (int it = 0; it < 16; ++it) {
        int buf = it & 1;
        *(bf16x8*)&Ks[buf][kw_idx] = kreg;
        *(bf16x8*)&Vs[buf][vw_idx] = vreg;
        __syncthreads();
        if (it < 15) {     // issue next-tile loads AFTER barrier so drain doesn't eat them
            kreg = *(const bf16x8*)(kgp + (size_t)(it + 1) * 64 * DH);
            vreg = *(const bf16x8*)(vgp + (it + 1) * 64);
        }
        // S^T: 2 m-subtiles x (K=32 as 2 chained k16 MFMAs)
        f32x16 s0, s1;
        {
            bf16x8 a00 = *(const bf16x8*)&Ks[buf][kro[0][0]];
            bf16x8 a01 = *(const bf16x8*)&Ks[buf][kro[0][1]];
            s0 = __builtin_amdgcn_mfma_f32_32x32x16_bf16(a00, bq0, zero16, 0, 0, 0);
            s0 = __builtin_amdgcn_mfma_f32_32x32x16_bf16(a01, bq1, s0, 0, 0, 0);
            bf16x8 a10 = *(const bf16x8*)&Ks[buf][kro[1][0]];
            bf16x8 a11 = *(const bf16x8*)&Ks[buf][kro[1][1]];
            s1 = __builtin_amdgcn_mfma_f32_32x32x16_bf16(a10, bq0, zero16, 0, 0, 0);
            s1 = __builtin_amdgcn_mfma_f32_32x32x16_bf16(a11, bq1, s1, 0, 0, 0);
        }
        // p = FASTEXP(s); pack pairs by truncation (KFOLD in K; fixed max=0, |s|<<1)
        unsigned pk[2][8];
#pragma unroll
        for (int qq = 0; qq < 8; ++qq) {
            float e0 = FASTEXP(s0[2 * qq]), e1 = FASTEXP(s0[2 * qq + 1]);
            l_part += e0 + e1;
            pk[0][qq] = pack2bf_t(e0, e1);
            float f0 = FASTEXP(s1[2 * qq]), f1 = FASTEXP(s1[2 * qq + 1]);
            l_part += f0 + f1;
            pk[1][qq] = pack2bf_t(f0, f1);
        }
        // PV: B-frag = direct reinterpret of pk (V m-permutation absorbs layout)
#pragma unroll
        for (int kc = 0; kc < 4; ++kc) {
            int ms = kc >> 1, Qb = 4 * (kc & 1);
            union { unsigned u[4]; bf16x8 v; } bu;
            bu.u[0] = pk[ms][Qb + 0];
            bu.u[1] = pk[ms][Qb + 1];
            bu.u[2] = pk[ms][Qb + 2];
            bu.u[3] = pk[ms][Qb + 3];
            bf16x8 av = *(const bf16x8*)&Vs[buf][vro[kc]];
            accO = __builtin_amdgcn_mfma_f32_32x32x16_bf16(av, bu.v, accO, 0, 0, 0);
        }
    }
    // partial l: combine the two lane-halves of each column
    l_part += __shfl_xor(l_part, 32, 64);
    size_t obase = (size_t)mpart * (4 * CH * HW) + (size_t)b * CH * HW;
#pragma unroll
    for (int r = 0; r < 16; ++r) {
        int d = (r & 3) + 8 * (r >> 2) + 4 * hf;
        Op[obase + (size_t)(d * NH + hh) * HW + n_g] = f2bf(accO[r]);
    }
    if (hf == 0) lp[(size_t)(mpart * 16 + bh) * HW + n_g] = l_part;
}

// ---------------- Output projection (fused combine) + bias + residual ----
// grid (128 p-tiles of 32, B) x 256. Staging sums 4 bf16 partials, divides by
// summed l, builds bf16 [p][c] tile, then MFMA GEMM + residual.
__global__ __launch_bounds__(256) void proj_mfma_kernel(
    const u16* __restrict__ Op, const float* __restrict__ lp,
    const u16* __restrict__ wp, const float* __restrict__ proj_b,
    const float* __restrict__ x, float* __restrict__ out) {
    __shared__ u16 at_t[32 * 136];   // [p][c] pitch 136
    int b = blockIdx.y, p0 = blockIdx.x * 32, t = threadIdx.x;
#pragma unroll
    for (int i = 0; i < 4; ++i) {
        int u = t + 256 * i;                 // 1024 u16x4 quads
        int c = u & 127, p4 = (u >> 7) * 4;
        int bh = b * NH + (c & 3);
        float ls0 = 0.f, ls1 = 0.f, ls2 = 0.f, ls3 = 0.f;
        float o0 = 0.f, o1 = 0.f, o2 = 0.f, o3 = 0.f;
#pragma unroll
        for (int part = 0; part < 4; ++part) {
            float4 lv = *(const float4*)&lp[(size_t)(part * 16 + bh) * HW + p0 + p4];
            ls0 += lv.x; ls1 += lv.y; ls2 += lv.z; ls3 += lv.w;
            u16x4 ov = *(const u16x4*)&Op[(size_t)part * (4 * CH * HW)
                                          + ((size_t)b * CH + c) * HW + p0 + p4];
            o0 += bf2f(ov[0]); o1 += bf2f(ov[1]); o2 += bf2f(ov[2]); o3 += bf2f(ov[3]);
        }
        at_t[(p4 + 0) * 136 + c] = f2bf(o0 * RCPF(ls0));
        at_t[(p4 + 1) * 136 + c] = f2bf(o1 * RCPF(ls1));
        at_t[(p4 + 2) * 136 + c] = f2bf(o2 * RCPF(ls2));
        at_t[(p4 + 3) * 136 + c] = f2bf(o3 * RCPF(ls3));
    }
    __syncthreads();
    int wave = t >> 6, lane = t & 63, l16 = lane & 15, quad = lane >> 4;
    f32x4 acc[2][2];
#pragma unroll
    for (int os = 0; os < 2; ++os)
#pragma unroll
        for (int ps = 0; ps < 2; ++ps) acc[os][ps] = f32x4{0.f, 0.f, 0.f, 0.f};
#pragma unroll
    for (int kc = 0; kc < 4; ++kc) {
        bf16x8 bfr[2];
#pragma unroll
        for (int ps = 0; ps < 2; ++ps)
            bfr[ps] = *(const bf16x8*)&at_t[(ps * 16 + l16) * 136 + kc * 32 + quad * 8];
#pragma unroll
        for (int os = 0; os < 2; ++os) {
            bf16x8 af = *(const bf16x8*)&wp[(size_t)(wave * 32 + os * 16 + l16) * 128 + kc * 32 + quad * 8];
#pragma unroll
            for (int ps = 0; ps < 2; ++ps)
                acc[os][ps] = __builtin_amdgcn_mfma_f32_16x16x32_bf16(af, bfr[ps], acc[os][ps], 0, 0, 0);
        }
    }
#pragma unroll
    for (int os = 0; os < 2; ++os) {
        int obase = wave * 32 + os * 16 + quad * 4;
#pragma unroll
        for (int ps = 0; ps < 2; ++ps) {
            int p = p0 + ps * 16 + l16;
#pragma unroll
            for (int r = 0; r < 4; ++r) {
                size_t idx = ((size_t)b * CH + obase + r) * HW + p;
                out[idx] = acc[os][ps][r] + proj_b[obase + r] + x[idx];
            }
        }
    }
}

extern "C" void kernel_launch(void* const* d_in, const int* in_sizes, int n_in,
                              void* d_out, int out_size, void* d_ws, size_t ws_size,
                              hipStream_t stream) {
    const float* x      = (const float*)d_in[0];
    const float* gn_w   = (const float*)d_in[1];
    const float* gn_b   = (const float*)d_in[2];
    const float* qkv_w  = (const float*)d_in[3];
    const float* qkv_b  = (const float*)d_in[4];
    const float* proj_w = (const float*)d_in[5];
    const float* proj_b = (const float*)d_in[6];
    float* out = (float*)d_out;

    char* W = (char*)d_ws;
    float* partials = (float*)(W + 0);                 // 4 KB
    u16*   wq       = (u16*)(W + 8192);                // 96 KB
    u16*   wp       = (u16*)(W + 8192 + 98304);        // 32 KB -> ends 139264
    u16*   qo       = (u16*)(W + 139264);              // 4 MB each
    u16*   ko       = qo + (size_t)2097152;
    u16*   vo       = ko + (size_t)2097152;
    u16*   Op       = vo + (size_t)2097152;            // bf16, 4 parts x 4 MB = 16 MB
    float* lp       = (float*)(Op + (size_t)4 * 2097152);  // 1 MB -> total ~30.5 MB

    hipLaunchKernelGGL(prep_kernel,      dim3(768),       dim3(256), 0, stream,
                       x, partials, qkv_w, proj_w, wq, wp);
    hipLaunchKernelGGL(qkv_mfma_kernel,  dim3(128, 4),    dim3(256), 0, stream,
                       x, gn_w, gn_b, wq, qkv_b, partials, qo, ko, vo);
    hipLaunchKernelGGL(attn_mfma_kernel, dim3(32, 4, 16), dim3(256), 0, stream,
                       qo, ko, vo, Op, lp);
    hipLaunchKernelGGL(proj_mfma_kernel, dim3(128, 4),    dim3(256), 0, stream,
                       Op, lp, wp, proj_b, x, out);
}

// Round 7
// 150.768 us; speedup vs baseline: 1.3211x; 1.0825x over previous
//
#include <hip/hip_runtime.h>
#include <math.h>

#define HW 4096
#define CH 128
#define NH 4
#define DH 32

typedef unsigned short u16;
typedef __attribute__((ext_vector_type(8))) short bf16x8;   // 8 bf16 in 4 VGPRs
typedef __attribute__((ext_vector_type(4))) float f32x4;
typedef __attribute__((ext_vector_type(16))) float f32x16;
typedef __attribute__((ext_vector_type(4))) unsigned short u16x4;
typedef __attribute__((ext_vector_type(8))) unsigned short u16x8;

// raw v_exp_f32 (args are in [-1,1]; no range fixups needed)
#if __has_builtin(__builtin_amdgcn_exp2f)
#define KFOLD (0.17677669529663687f * 1.4426950408889634f)   // scale * log2(e)
#define FASTEXP(x) __builtin_amdgcn_exp2f(x)
#else
#define KFOLD 0.17677669529663687f                            // scale only
#define FASTEXP(x) __expf(x)
#endif

#if __has_builtin(__builtin_amdgcn_rcpf)
#define RCPF(x) __builtin_amdgcn_rcpf(x)
#else
#define RCPF(x) (1.f / (x))
#endif

__device__ __forceinline__ u16 f2bf(float f) {
    union { float f; unsigned u; } a; a.f = f;
    unsigned u = a.u;
    unsigned r = u + 0x7FFFu + ((u >> 16) & 1u);   // RNE
    return (u16)(r >> 16);
}
__device__ __forceinline__ float bf2f(u16 u) {
    union { unsigned u; float f; } a; a.u = ((unsigned)u) << 16;
    return a.f;
}
// pack two positive floats to bf16 pair by TRUNCATION (1 v_perm): low=a, high=b
__device__ __forceinline__ unsigned pack2bf_t(float a, float b) {
    union { float f; unsigned u; } ua, ub; ua.f = a; ub.f = b;
    return __builtin_amdgcn_perm(ub.u, ua.u, 0x07060302u);
}

// ---------------- Fused: weight bf16 conversion + GroupNorm partials ------
__global__ __launch_bounds__(256) void prep_kernel(
    const float* __restrict__ x, float* __restrict__ partials,
    const float* __restrict__ qkv_w, const float* __restrict__ proj_w,
    u16* __restrict__ wq, u16* __restrict__ wp) {
    int blk = blockIdx.x, t = threadIdx.x;
    if (blk < 512) {
        const float4* xv = (const float4*)(x + (size_t)blk * 4096);
        float s = 0.f, sq = 0.f;
#pragma unroll
        for (int i = 0; i < 4; ++i) {
            float4 v = xv[t + 256 * i];
            s  += v.x + v.y + v.z + v.w;
            sq += v.x * v.x + v.y * v.y + v.z * v.z + v.w * v.w;
        }
#pragma unroll
        for (int off = 32; off > 0; off >>= 1) {
            s  += __shfl_down(s, off, 64);
            sq += __shfl_down(sq, off, 64);
        }
        __shared__ float red[8];
        int wave = t >> 6, lane = t & 63;
        if (lane == 0) { red[wave * 2] = s; red[wave * 2 + 1] = sq; }
        __syncthreads();
        if (t == 0) {
            partials[blk * 2]     = red[0] + red[2] + red[4] + red[6];
            partials[blk * 2 + 1] = red[1] + red[3] + red[5] + red[7];
        }
    } else {
        int i = (blk - 512) * 256 + t;              // [0, 65536)
        if (i < 49152) wq[i] = f2bf(qkv_w[i]);
        else           wp[i - 49152] = f2bf(proj_w[i - 49152]);
    }
}

// ---------------- QKV projection via MFMA (inline GN finalize) ------------
// grid (128 p-tiles of 32, B) x 256. q,k out as [b][h][n][32d] bf16 (k pre-scaled
// by KFOLD); v as [b][h][32d][m] bf16, m-permuted (bits 2<->3), written via an
// LDS transpose so global stores are coalesced 64B row segments.
__global__ __launch_bounds__(256) void qkv_mfma_kernel(
    const float* __restrict__ x, const float* __restrict__ gn_w, const float* __restrict__ gn_b,
    const u16* __restrict__ wq, const float* __restrict__ qkv_b, const float* __restrict__ partials,
    u16* __restrict__ qo, u16* __restrict__ ko, u16* __restrict__ vo) {
    __shared__ u16 xt[32 * 136];   // [p][c] pitch 136; reused as vt[128 oc][32 m] pitch 34
    __shared__ float sstats[2];
    int b = blockIdx.y, p0 = blockIdx.x * 32, t = threadIdx.x;
    const float* xb = x + (size_t)b * CH * HW;
    float4 xv[4]; int cc[4], pp[4];
#pragma unroll
    for (int i = 0; i < 4; ++i) {
        int u = t + 256 * i;
        cc[i] = u & 127; pp[i] = (u >> 7) * 4;
        xv[i] = *(const float4*)&xb[(size_t)cc[i] * HW + p0 + pp[i]];
    }
    if (t < 64) {   // per-block redundant GN finalize (2 KB L2 read, one wave)
        float s  = partials[(b * 128 + t) * 2]     + partials[(b * 128 + 64 + t) * 2];
        float sq = partials[(b * 128 + t) * 2 + 1] + partials[(b * 128 + 64 + t) * 2 + 1];
#pragma unroll
        for (int off = 32; off > 0; off >>= 1) {
            s  += __shfl_down(s, off, 64);
            sq += __shfl_down(sq, off, 64);
        }
        if (t == 0) {
            const float invN = 1.f / (float)(CH * HW);
            float mean = s * invN;
            float var  = sq * invN - mean * mean;
            sstats[0] = mean;
            sstats[1] = rsqrtf(var + 1e-5f);
        }
    }
    __syncthreads();
    float mean = sstats[0], rstd = sstats[1];
#pragma unroll
    for (int i = 0; i < 4; ++i) {
        float sc = rstd * gn_w[cc[i]], bb = gn_b[cc[i]] - mean * sc;
        xt[(pp[i] + 0) * 136 + cc[i]] = f2bf(fmaf(xv[i].x, sc, bb));
        xt[(pp[i] + 1) * 136 + cc[i]] = f2bf(fmaf(xv[i].y, sc, bb));
        xt[(pp[i] + 2) * 136 + cc[i]] = f2bf(fmaf(xv[i].z, sc, bb));
        xt[(pp[i] + 3) * 136 + cc[i]] = f2bf(fmaf(xv[i].w, sc, bb));
    }
    __syncthreads();
    int wave = t >> 6, lane = t & 63, l16 = lane & 15, quad = lane >> 4;
    f32x4 acc[6][2];
#pragma unroll
    for (int os = 0; os < 6; ++os)
#pragma unroll
        for (int ps = 0; ps < 2; ++ps) acc[os][ps] = f32x4{0.f, 0.f, 0.f, 0.f};
#pragma unroll
    for (int kc = 0; kc < 4; ++kc) {
        bf16x8 bfr[2];
#pragma unroll
        for (int ps = 0; ps < 2; ++ps)
            bfr[ps] = *(const bf16x8*)&xt[(ps * 16 + l16) * 136 + kc * 32 + quad * 8];
#pragma unroll
        for (int os = 0; os < 6; ++os) {
            bf16x8 af = *(const bf16x8*)&wq[(size_t)(wave * 96 + os * 16 + l16) * 128 + kc * 32 + quad * 8];
#pragma unroll
            for (int ps = 0; ps < 2; ++ps)
                acc[os][ps] = __builtin_amdgcn_mfma_f32_16x16x32_bf16(af, bfr[ps], acc[os][ps], 0, 0, 0);
        }
    }
    // ---- pass 1: q,k direct stores ----
#pragma unroll
    for (int os = 0; os < 6; ++os) {
        int obase = wave * 96 + os * 16 + quad * 4;
        int sec = obase >> 7;              // wave-uniform
        if (sec == 2) continue;
        float4 bias = *(const float4*)&qkv_b[obase];
        int oc = obase & 127, h = oc >> 5, d = oc & 31;
        float km = (sec == 1) ? KFOLD : 1.f;
#pragma unroll
        for (int ps = 0; ps < 2; ++ps) {
            int p = p0 + ps * 16 + l16;
            u16x4 pk = {f2bf((acc[os][ps][0] + bias.x) * km),
                        f2bf((acc[os][ps][1] + bias.y) * km),
                        f2bf((acc[os][ps][2] + bias.z) * km),
                        f2bf((acc[os][ps][3] + bias.w) * km)};
            *(u16x4*)((sec == 0 ? qo : ko) + ((size_t)(b * NH + h) * HW + p) * DH + d) = pk;
        }
    }
    // ---- pass 2: v through LDS transpose ----
    __syncthreads();          // xt fully consumed by all waves
    u16* vt = xt;             // [128 oc][32 m] pitch 34 (4352 u16 == xt size)
    int l16p2 = (l16 & 3) | ((l16 & 4) << 1) | ((l16 & 8) >> 1);   // m-bit 2<->3 swap
#pragma unroll
    for (int os = 0; os < 6; ++os) {
        int obase = wave * 96 + os * 16 + quad * 4;
        if ((obase >> 7) != 2) continue;
        float4 bias = *(const float4*)&qkv_b[obase];
        int oc = obase & 127;
#pragma unroll
        for (int ps = 0; ps < 2; ++ps) {
            int colm = ps * 16 + l16p2;
            vt[(oc + 0) * 34 + colm] = f2bf(acc[os][ps][0] + bias.x);
            vt[(oc + 1) * 34 + colm] = f2bf(acc[os][ps][1] + bias.y);
            vt[(oc + 2) * 34 + colm] = f2bf(acc[os][ps][2] + bias.z);
            vt[(oc + 3) * 34 + colm] = f2bf(acc[os][ps][3] + bias.w);
        }
    }
    __syncthreads();
#pragma unroll
    for (int i = 0; i < 2; ++i) {
        int row = i * 64 + (t >> 2), colv = (t & 3) * 8;   // row = b-local vo row (h*32+d)
        *(u16x8*)&vo[((size_t)b * CH + row) * HW + p0 + colv] = *(const u16x8*)&vt[row * 34 + colv];
    }
}

// ---------------- Flash attention, 32x32x16 MFMA, 6-way m-split -----------
// grid (32 n-tiles of 128, 6 m-parts, 16 bh) x 256; parts 0-3: 11 tiles,
// 4-5: 10 tiles (even 2-generation residency at 6 blocks/CU). Epilogue
// transposes O^T via LDS -> Op[part][bh][n][32d] coalesced; lp [bh][n][8].
__global__ __launch_bounds__(256) void attn_mfma_kernel(
    const u16* __restrict__ q, const u16* __restrict__ k, const u16* __restrict__ v,
    u16* __restrict__ Op, float* __restrict__ lp) {
    __shared__ u16 smem[8192];   // Ks: 2x2048 @0; Vs: 2x2048 @4096; epi: 128x36
    int bh = blockIdx.z, mpart = blockIdx.y, t = threadIdx.x;
    int wave = t >> 6, lane = t & 63, l31 = lane & 31, hf = lane >> 5;
    const u16* qb = q + (size_t)bh * HW * DH;
    const u16* kb = k + (size_t)bh * HW * DH;   // pre-scaled by KFOLD
    const u16* vb = v + (size_t)bh * DH * HW;
    int n_g = blockIdx.x * 128 + wave * 32 + l31;
    int start_t = mpart * 11 - (mpart == 5 ? 1 : 0);
    int nt = (mpart < 4) ? 11 : 10;
    int m_base = start_t * 64;

    bf16x8 bq0 = *(const bf16x8*)&qb[(size_t)n_g * DH + hf * 8];
    bf16x8 bq1 = *(const bf16x8*)&qb[(size_t)n_g * DH + 16 + hf * 8];

    int km_ = t >> 2, kg_ = t & 3;
    int kw_idx = km_ * 32 + ((kg_ ^ (km_ & 3) ^ ((km_ >> 2) & 1)) * 8);
    const u16* kgp = kb + (size_t)(m_base + km_) * DH + kg_ * 8;
    int vd_ = t >> 3, vg_ = t & 7;
    int vw_idx = vd_ * 64 + ((vg_ ^ (vd_ & 7)) * 8);
    const u16* vgp = vb + (size_t)vd_ * HW + m_base + vg_ * 8;

    int kswz = (l31 & 3) ^ ((l31 >> 2) & 1);
    int kro[2][2], vro[4];
#pragma unroll
    for (int ms = 0; ms < 2; ++ms)
#pragma unroll
        for (int kc = 0; kc < 2; ++kc)
            kro[ms][kc] = (ms * 32 + l31) * 32 + (((2 * kc + hf) ^ kswz) * 8);
#pragma unroll
    for (int kc = 0; kc < 4; ++kc)
        vro[kc] = l31 * 64 + (((2 * kc + hf) ^ (l31 & 7)) * 8);

    const f32x16 zero16 = {0.f,0.f,0.f,0.f,0.f,0.f,0.f,0.f,0.f,0.f,0.f,0.f,0.f,0.f,0.f,0.f};
    f32x16 accO = zero16;
    float l_part = 0.f;

    bf16x8 kreg = *(const bf16x8*)kgp;
    bf16x8 vreg = *(const bf16x8*)vgp;

    for (int it = 0; it < nt; ++it) {
        u16* Ksb = smem + (it & 1) * 2048;
        u16* Vsb = smem + 4096 + (it & 1) * 2048;
        Ksb[0] = Ksb[0];   // no-op
        *(bf16x8*)&Ksb[kw_idx] = kreg;
        *(bf16x8*)&Vsb[vw_idx] = vreg;
        __syncthreads();
        if (it + 1 < nt) {   // issue next-tile loads AFTER barrier
            kreg = *(const bf16x8*)(kgp + (size_t)(it + 1) * 64 * DH);
            vreg = *(const bf16x8*)(vgp + (it + 1) * 64);
        }
        f32x16 s0, s1;
        {
            bf16x8 a00 = *(const bf16x8*)&Ksb[kro[0][0]];
            bf16x8 a01 = *(const bf16x8*)&Ksb[kro[0][1]];
            s0 = __builtin_amdgcn_mfma_f32_32x32x16_bf16(a00, bq0, zero16, 0, 0, 0);
            s0 = __builtin_amdgcn_mfma_f32_32x32x16_bf16(a01, bq1, s0, 0, 0, 0);
            bf16x8 a10 = *(const bf16x8*)&Ksb[kro[1][0]];
            bf16x8 a11 = *(const bf16x8*)&Ksb[kro[1][1]];
            s1 = __builtin_amdgcn_mfma_f32_32x32x16_bf16(a10, bq0, zero16, 0, 0, 0);
            s1 = __builtin_amdgcn_mfma_f32_32x32x16_bf16(a11, bq1, s1, 0, 0, 0);
        }
        unsigned pk[2][8];
#pragma unroll
        for (int qq = 0; qq < 8; ++qq) {
            float e0 = FASTEXP(s0[2 * qq]), e1 = FASTEXP(s0[2 * qq + 1]);
            l_part += e0 + e1;
            pk[0][qq] = pack2bf_t(e0, e1);
            float f0 = FASTEXP(s1[2 * qq]), f1 = FASTEXP(s1[2 * qq + 1]);
            l_part += f0 + f1;
            pk[1][qq] = pack2bf_t(f0, f1);
        }
#pragma unroll
        for (int kc = 0; kc < 4; ++kc) {
            int ms = kc >> 1, Qb = 4 * (kc & 1);
            union { unsigned u[4]; bf16x8 v; } bu;
            bu.u[0] = pk[ms][Qb + 0];
            bu.u[1] = pk[ms][Qb + 1];
            bu.u[2] = pk[ms][Qb + 2];
            bu.u[3] = pk[ms][Qb + 3];
            bf16x8 av = *(const bf16x8*)&Vsb[vro[kc]];
            accO = __builtin_amdgcn_mfma_f32_32x32x16_bf16(av, bu.v, accO, 0, 0, 0);
        }
    }
    l_part += __shfl_xor(l_part, 32, 64);
    if (hf == 0) lp[((size_t)bh * HW + n_g) * 8 + mpart] = l_part;
    // epilogue: transpose O^T (C-layout) -> [n][d] in LDS, coalesced store
    __syncthreads();
    u16* tb = smem;                      // [128 n][32 d] pitch 36
    int nloc = wave * 32 + l31;
#pragma unroll
    for (int r = 0; r < 16; ++r) {
        int d = (r & 3) + 8 * (r >> 2) + 4 * hf;
        tb[nloc * 36 + d] = f2bf(accO[r]);
    }
    __syncthreads();
    size_t obase = ((size_t)(mpart * 16 + bh) * HW + blockIdx.x * 128) * 32;
#pragma unroll
    for (int i = 0; i < 2; ++i) {
        int row = i * 64 + (t >> 2), col = (t & 3) * 8;
        *(u16x8*)&Op[obase + (size_t)row * 32 + col] = *(const u16x8*)&tb[row * 36 + col];
    }
}

// ---------------- Output projection (fused combine) + bias + residual ----
// grid (128 p-tiles of 32, B) x 256. Staging: coalesced Op[part][bh][n][32d]
// reads, 6-part fp32 sum, divide by summed l, LDS tile [p][c], MFMA GEMM.
__global__ __launch_bounds__(256) void proj_mfma_kernel(
    const u16* __restrict__ Op, const float* __restrict__ lp,
    const u16* __restrict__ wp, const float* __restrict__ proj_b,
    const float* __restrict__ x, float* __restrict__ out) {
    __shared__ u16 at_t[32 * 136];   // [p][c] pitch 136
    int b = blockIdx.y, p0 = blockIdx.x * 32, t = threadIdx.x;
#pragma unroll
    for (int i = 0; i < 2; ++i) {
        int u = t + 256 * i;                 // 512 units: p(32) x hh(4) x chunk(4)
        int p = u >> 4, hh = (u >> 2) & 3, ch = u & 3;
        int bh = b * NH + hh;
        size_t nidx = (size_t)bh * HW + p0 + p;
        float4 l4 = *(const float4*)&lp[nidx * 8];
        float2 l2 = *(const float2*)&lp[nidx * 8 + 4];
        float lsum = ((l4.x + l4.y) + (l4.z + l4.w)) + (l2.x + l2.y);
        float sum8[8] = {0.f,0.f,0.f,0.f,0.f,0.f,0.f,0.f};
#pragma unroll
        for (int part = 0; part < 6; ++part) {
            u16x8 ov = *(const u16x8*)&Op[((size_t)(part * 16 + bh) * HW + p0 + p) * 32 + ch * 8];
#pragma unroll
            for (int j = 0; j < 8; ++j) sum8[j] += bf2f(ov[j]);
        }
        float rin = RCPF(lsum);
#pragma unroll
        for (int j = 0; j < 8; ++j)
            at_t[p * 136 + (ch * 8 + j) * 4 + hh] = f2bf(sum8[j] * rin);
    }
    __syncthreads();
    int wave = t >> 6, lane = t & 63, l16 = lane & 15, quad = lane >> 4;
    f32x4 acc[2][2];
#pragma unroll
    for (int os = 0; os < 2; ++os)
#pragma unroll
        for (int ps = 0; ps < 2; ++ps) acc[os][ps] = f32x4{0.f, 0.f, 0.f, 0.f};
#pragma unroll
    for (int kc = 0; kc < 4; ++kc) {
        bf16x8 bfr[2];
#pragma unroll
        for (int ps = 0; ps < 2; ++ps)
            bfr[ps] = *(const bf16x8*)&at_t[(ps * 16 + l16) * 136 + kc * 32 + quad * 8];
#pragma unroll
        for (int os = 0; os < 2; ++os) {
            bf16x8 af = *(const bf16x8*)&wp[(size_t)(wave * 32 + os * 16 + l16) * 128 + kc * 32 + quad * 8];
#pragma unroll
            for (int ps = 0; ps < 2; ++ps)
                acc[os][ps] = __builtin_amdgcn_mfma_f32_16x16x32_bf16(af, bfr[ps], acc[os][ps], 0, 0, 0);
        }
    }
#pragma unroll
    for (int os = 0; os < 2; ++os) {
        int obase = wave * 32 + os * 16 + quad * 4;
#pragma unroll
        for (int ps = 0; ps < 2; ++ps) {
            int p = p0 + ps * 16 + l16;
#pragma unroll
            for (int r = 0; r < 4; ++r) {
                size_t idx = ((size_t)b * CH + obase + r) * HW + p;
                out[idx] = acc[os][ps][r] + proj_b[obase + r] + x[idx];
            }
        }
    }
}

extern "C" void kernel_launch(void* const* d_in, const int* in_sizes, int n_in,
                              void* d_out, int out_size, void* d_ws, size_t ws_size,
                              hipStream_t stream) {
    const float* x      = (const float*)d_in[0];
    const float* gn_w   = (const float*)d_in[1];
    const float* gn_b   = (const float*)d_in[2];
    const float* qkv_w  = (const float*)d_in[3];
    const float* qkv_b  = (const float*)d_in[4];
    const float* proj_w = (const float*)d_in[5];
    const float* proj_b = (const float*)d_in[6];
    float* out = (float*)d_out;

    char* W = (char*)d_ws;
    float* partials = (float*)(W + 0);                 // 4 KB
    u16*   wq       = (u16*)(W + 8192);                // 96 KB
    u16*   wp       = (u16*)(W + 8192 + 98304);        // 32 KB -> ends 139264
    u16*   qo       = (u16*)(W + 139264);              // 4 MB each
    u16*   ko       = qo + (size_t)2097152;
    u16*   vo       = ko + (size_t)2097152;
    u16*   Op       = vo + (size_t)2097152;            // 6 parts x 4 MB = 24 MB
    float* lp       = (float*)(Op + (size_t)6 * 2097152);  // 2 MB -> total ~40 MB

    hipLaunchKernelGGL(prep_kernel,      dim3(768),       dim3(256), 0, stream,
                       x, partials, qkv_w, proj_w, wq, wp);
    hipLaunchKernelGGL(qkv_mfma_kernel,  dim3(128, 4),    dim3(256), 0, stream,
                       x, gn_w, gn_b, wq, qkv_b, partials, qo, ko, vo);
    hipLaunchKernelGGL(attn_mfma_kernel, dim3(32, 6, 16), dim3(256), 0, stream,
                       qo, ko, vo, Op, lp);
    hipLaunchKernelGGL(proj_mfma_kernel, dim3(128, 4),    dim3(256), 0, stream,
                       Op, lp, wp, proj_b, x, out);
}

// Round 8
// 143.717 us; speedup vs baseline: 1.3859x; 1.0491x over previous
//
#include <hip/hip_runtime.h>
#include <math.h>

#define HW 4096
#define CH 128
#define NH 4
#define DH 32

typedef unsigned short u16;
typedef __attribute__((ext_vector_type(8))) short bf16x8;   // 8 bf16 in 4 VGPRs
typedef __attribute__((ext_vector_type(4))) float f32x4;
typedef __attribute__((ext_vector_type(16))) float f32x16;
typedef __attribute__((ext_vector_type(4))) unsigned short u16x4;
typedef __attribute__((ext_vector_type(8))) unsigned short u16x8;

// raw v_exp_f32 (args are in [-1,1]; no range fixups needed)
#if __has_builtin(__builtin_amdgcn_exp2f)
#define KFOLD (0.17677669529663687f * 1.4426950408889634f)   // scale * log2(e)
#define FASTEXP(x) __builtin_amdgcn_exp2f(x)
#else
#define KFOLD 0.17677669529663687f                            // scale only
#define FASTEXP(x) __expf(x)
#endif

#if __has_builtin(__builtin_amdgcn_rcpf)
#define RCPF(x) __builtin_amdgcn_rcpf(x)
#else
#define RCPF(x) (1.f / (x))
#endif

__device__ __forceinline__ u16 f2bf(float f) {
    union { float f; unsigned u; } a; a.f = f;
    unsigned u = a.u;
    unsigned r = u + 0x7FFFu + ((u >> 16) & 1u);   // RNE
    return (u16)(r >> 16);
}
__device__ __forceinline__ float bf2f(u16 u) {
    union { unsigned u; float f; } a; a.u = ((unsigned)u) << 16;
    return a.f;
}
// pack two positive floats to bf16 pair by TRUNCATION (1 v_perm): low=a, high=b
__device__ __forceinline__ unsigned pack2bf_t(float a, float b) {
    union { float f; unsigned u; } ua, ub; ua.f = a; ub.f = b;
    return __builtin_amdgcn_perm(ub.u, ua.u, 0x07060302u);
}

// ---------------- Fused: weight bf16 conversion + GroupNorm partials ------
__global__ __launch_bounds__(256) void prep_kernel(
    const float* __restrict__ x, float* __restrict__ partials,
    const float* __restrict__ qkv_w, const float* __restrict__ proj_w,
    u16* __restrict__ wq, u16* __restrict__ wp) {
    int blk = blockIdx.x, t = threadIdx.x;
    if (blk < 512) {
        const float4* xv = (const float4*)(x + (size_t)blk * 4096);
        float s = 0.f, sq = 0.f;
#pragma unroll
        for (int i = 0; i < 4; ++i) {
            float4 v = xv[t + 256 * i];
            s  += v.x + v.y + v.z + v.w;
            sq += v.x * v.x + v.y * v.y + v.z * v.z + v.w * v.w;
        }
#pragma unroll
        for (int off = 32; off > 0; off >>= 1) {
            s  += __shfl_down(s, off, 64);
            sq += __shfl_down(sq, off, 64);
        }
        __shared__ float red[8];
        int wave = t >> 6, lane = t & 63;
        if (lane == 0) { red[wave * 2] = s; red[wave * 2 + 1] = sq; }
        __syncthreads();
        if (t == 0) {
            partials[blk * 2]     = red[0] + red[2] + red[4] + red[6];
            partials[blk * 2 + 1] = red[1] + red[3] + red[5] + red[7];
        }
    } else {
        int i = (blk - 512) * 256 + t;              // [0, 65536)
        if (i < 49152) wq[i] = f2bf(qkv_w[i]);
        else           wp[i - 49152] = f2bf(proj_w[i - 49152]);
    }
}

// ---------------- QKV projection via MFMA (inline GN finalize) ------------
// grid (128 p-tiles of 32, B) x 256. COALESCED x loads (8 lanes span one
// channel row). q,k out as [b][h][n][32d] bf16 (k pre-scaled by KFOLD);
// v as [b][h][32d][m] bf16, m-permuted (bits 2<->3), via LDS transpose.
__global__ __launch_bounds__(256) void qkv_mfma_kernel(
    const float* __restrict__ x, const float* __restrict__ gn_w, const float* __restrict__ gn_b,
    const u16* __restrict__ wq, const float* __restrict__ qkv_b, const float* __restrict__ partials,
    u16* __restrict__ qo, u16* __restrict__ ko, u16* __restrict__ vo) {
    __shared__ u16 xt[32 * 136];   // [p][c] pitch 136; reused as vt[128 oc][32 m] pitch 34
    __shared__ float sstats[2];
    int b = blockIdx.y, p0 = blockIdx.x * 32, t = threadIdx.x;
    const float* xb = x + (size_t)b * CH * HW;
    float4 xv[4]; int cc[4], pp[4];
#pragma unroll
    for (int i = 0; i < 4; ++i) {
        int u = t + 256 * i;
        cc[i] = u >> 3; pp[i] = (u & 7) * 4;      // coalesced: 8 lanes per c-row
        xv[i] = *(const float4*)&xb[(size_t)cc[i] * HW + p0 + pp[i]];
    }
    if (t < 64) {   // per-block redundant GN finalize (2 KB L2 read, one wave)
        float s  = partials[(b * 128 + t) * 2]     + partials[(b * 128 + 64 + t) * 2];
        float sq = partials[(b * 128 + t) * 2 + 1] + partials[(b * 128 + 64 + t) * 2 + 1];
#pragma unroll
        for (int off = 32; off > 0; off >>= 1) {
            s  += __shfl_down(s, off, 64);
            sq += __shfl_down(sq, off, 64);
        }
        if (t == 0) {
            const float invN = 1.f / (float)(CH * HW);
            float mean = s * invN;
            float var  = sq * invN - mean * mean;
            sstats[0] = mean;
            sstats[1] = rsqrtf(var + 1e-5f);
        }
    }
    __syncthreads();
    float mean = sstats[0], rstd = sstats[1];
#pragma unroll
    for (int i = 0; i < 4; ++i) {
        float sc = rstd * gn_w[cc[i]], bb = gn_b[cc[i]] - mean * sc;
        xt[(pp[i] + 0) * 136 + cc[i]] = f2bf(fmaf(xv[i].x, sc, bb));
        xt[(pp[i] + 1) * 136 + cc[i]] = f2bf(fmaf(xv[i].y, sc, bb));
        xt[(pp[i] + 2) * 136 + cc[i]] = f2bf(fmaf(xv[i].z, sc, bb));
        xt[(pp[i] + 3) * 136 + cc[i]] = f2bf(fmaf(xv[i].w, sc, bb));
    }
    __syncthreads();
    int wave = t >> 6, lane = t & 63, l16 = lane & 15, quad = lane >> 4;
    f32x4 acc[6][2];
#pragma unroll
    for (int os = 0; os < 6; ++os)
#pragma unroll
        for (int ps = 0; ps < 2; ++ps) acc[os][ps] = f32x4{0.f, 0.f, 0.f, 0.f};
#pragma unroll
    for (int kc = 0; kc < 4; ++kc) {
        bf16x8 bfr[2];
#pragma unroll
        for (int ps = 0; ps < 2; ++ps)
            bfr[ps] = *(const bf16x8*)&xt[(ps * 16 + l16) * 136 + kc * 32 + quad * 8];
#pragma unroll
        for (int os = 0; os < 6; ++os) {
            bf16x8 af = *(const bf16x8*)&wq[(size_t)(wave * 96 + os * 16 + l16) * 128 + kc * 32 + quad * 8];
#pragma unroll
            for (int ps = 0; ps < 2; ++ps)
                acc[os][ps] = __builtin_amdgcn_mfma_f32_16x16x32_bf16(af, bfr[ps], acc[os][ps], 0, 0, 0);
        }
    }
    // ---- pass 1: q,k direct stores ----
#pragma unroll
    for (int os = 0; os < 6; ++os) {
        int obase = wave * 96 + os * 16 + quad * 4;
        int sec = obase >> 7;              // wave-uniform
        if (sec == 2) continue;
        float4 bias = *(const float4*)&qkv_b[obase];
        int oc = obase & 127, h = oc >> 5, d = oc & 31;
        float km = (sec == 1) ? KFOLD : 1.f;
#pragma unroll
        for (int ps = 0; ps < 2; ++ps) {
            int p = p0 + ps * 16 + l16;
            u16x4 pk = {f2bf((acc[os][ps][0] + bias.x) * km),
                        f2bf((acc[os][ps][1] + bias.y) * km),
                        f2bf((acc[os][ps][2] + bias.z) * km),
                        f2bf((acc[os][ps][3] + bias.w) * km)};
            *(u16x4*)((sec == 0 ? qo : ko) + ((size_t)(b * NH + h) * HW + p) * DH + d) = pk;
        }
    }
    // ---- pass 2: v through LDS transpose ----
    __syncthreads();          // xt fully consumed by all waves
    u16* vt = xt;             // [128 oc][32 m] pitch 34
    int l16p2 = (l16 & 3) | ((l16 & 4) << 1) | ((l16 & 8) >> 1);   // m-bit 2<->3 swap
#pragma unroll
    for (int os = 0; os < 6; ++os) {
        int obase = wave * 96 + os * 16 + quad * 4;
        if ((obase >> 7) != 2) continue;
        float4 bias = *(const float4*)&qkv_b[obase];
        int oc = obase & 127;
#pragma unroll
        for (int ps = 0; ps < 2; ++ps) {
            int colm = ps * 16 + l16p2;
            vt[(oc + 0) * 34 + colm] = f2bf(acc[os][ps][0] + bias.x);
            vt[(oc + 1) * 34 + colm] = f2bf(acc[os][ps][1] + bias.y);
            vt[(oc + 2) * 34 + colm] = f2bf(acc[os][ps][2] + bias.z);
            vt[(oc + 3) * 34 + colm] = f2bf(acc[os][ps][3] + bias.w);
        }
    }
    __syncthreads();
#pragma unroll
    for (int i = 0; i < 2; ++i) {
        int row = i * 64 + (t >> 2), colv = (t & 3) * 8;
        *(u16x8*)&vo[((size_t)b * CH + row) * HW + p0 + colv] = *(const u16x8*)&vt[row * 34 + colv];
    }
}

// ---------------- Flash attention, 32x32x16 MFMA, 2-way m-split, 128-m tiles
// grid (32 n-tiles of 128, 2 m-parts, 16 bh) x 256 = 1024 blocks = exactly
// 4 blocks/CU, ONE generation. 16 iterations x 128 m per block; double-
// buffered K/V (32 KB LDS), one barrier per iteration.
__global__ __launch_bounds__(256, 4) void attn_mfma_kernel(
    const u16* __restrict__ q, const u16* __restrict__ k, const u16* __restrict__ v,
    u16* __restrict__ Op, float* __restrict__ lp) {
    __shared__ u16 smem[16384];  // Ks: 2x4096 @0; Vs: 2x4096 @8192; epi tb @0
    int bh = blockIdx.z, mpart = blockIdx.y, t = threadIdx.x;
    int wave = t >> 6, lane = t & 63, l31 = lane & 31, hf = lane >> 5;
    const u16* qb = q + (size_t)bh * HW * DH;
    const u16* kb = k + (size_t)bh * HW * DH;   // pre-scaled by KFOLD
    const u16* vb = v + (size_t)bh * DH * HW;
    int n_g = blockIdx.x * 128 + wave * 32 + l31;
    int m_base = mpart * 2048;

    bf16x8 bq0 = *(const bf16x8*)&qb[(size_t)n_g * DH + hf * 8];
    bf16x8 bq1 = *(const bf16x8*)&qb[(size_t)n_g * DH + 16 + hf * 8];

    // staging coords: K[128 m][32 d] (each thread 2 granules, halves m/m+64);
    // V[32 d][128 m] (each thread 2 granules, m-halves)
    int km_ = t >> 2, kg_ = t & 3;
    int kswz_w = (kg_ ^ (km_ & 3) ^ ((km_ >> 2) & 1)) * 8;
    int kw0 = km_ * 32 + kswz_w, kw1 = (km_ + 64) * 32 + kswz_w;
    const u16* kgp = kb + (size_t)(m_base + km_) * DH + kg_ * 8;
    int vd_ = t >> 3, vg_ = t & 7;
    int vswz = (vg_ ^ (vd_ & 7)) * 8;
    int vw0 = vd_ * 128 + vswz, vw1 = vd_ * 128 + 64 + vswz;
    const u16* vgp = vb + (size_t)vd_ * HW + m_base + vg_ * 8;

    // frag-read offsets
    int kswz_r = (l31 & 3) ^ ((l31 >> 2) & 1);
    int kro[2][2], vro[4];
#pragma unroll
    for (int ms = 0; ms < 2; ++ms)
#pragma unroll
        for (int kc = 0; kc < 2; ++kc)
            kro[ms][kc] = (ms * 32 + l31) * 32 + (((2 * kc + hf) ^ kswz_r) * 8);
#pragma unroll
    for (int kc = 0; kc < 4; ++kc)
        vro[kc] = l31 * 128 + (((2 * kc + hf) ^ (l31 & 7)) * 8);

    const f32x16 zero16 = {0.f,0.f,0.f,0.f,0.f,0.f,0.f,0.f,0.f,0.f,0.f,0.f,0.f,0.f,0.f,0.f};
    f32x16 accO = zero16;
    float l_part = 0.f;

    bf16x8 kregA = *(const bf16x8*)kgp;
    bf16x8 kregB = *(const bf16x8*)(kgp + 64 * DH);
    bf16x8 vregA = *(const bf16x8*)vgp;
    bf16x8 vregB = *(const bf16x8*)(vgp + 64);

    for (int it = 0; it < 16; ++it) {
        u16* Ksb = smem + (it & 1) * 4096;
        u16* Vsb = smem + 8192 + (it & 1) * 4096;
        *(bf16x8*)&Ksb[kw0] = kregA;
        *(bf16x8*)&Ksb[kw1] = kregB;
        *(bf16x8*)&Vsb[vw0] = vregA;
        *(bf16x8*)&Vsb[vw1] = vregB;
        __syncthreads();
        if (it < 15) {   // issue next-tile loads AFTER barrier
            const u16* kp = kgp + (size_t)(it + 1) * 128 * DH;
            kregA = *(const bf16x8*)kp;
            kregB = *(const bf16x8*)(kp + 64 * DH);
            const u16* vp = vgp + (it + 1) * 128;
            vregA = *(const bf16x8*)vp;
            vregB = *(const bf16x8*)(vp + 64);
        }
#pragma unroll
        for (int h = 0; h < 2; ++h) {       // two 64-m subtiles
            const u16* Kh = Ksb + h * 2048;
            f32x16 s0, s1;
            {
                bf16x8 a00 = *(const bf16x8*)&Kh[kro[0][0]];
                bf16x8 a01 = *(const bf16x8*)&Kh[kro[0][1]];
                s0 = __builtin_amdgcn_mfma_f32_32x32x16_bf16(a00, bq0, zero16, 0, 0, 0);
                s0 = __builtin_amdgcn_mfma_f32_32x32x16_bf16(a01, bq1, s0, 0, 0, 0);
                bf16x8 a10 = *(const bf16x8*)&Kh[kro[1][0]];
                bf16x8 a11 = *(const bf16x8*)&Kh[kro[1][1]];
                s1 = __builtin_amdgcn_mfma_f32_32x32x16_bf16(a10, bq0, zero16, 0, 0, 0);
                s1 = __builtin_amdgcn_mfma_f32_32x32x16_bf16(a11, bq1, s1, 0, 0, 0);
            }
            unsigned pk[2][8];
#pragma unroll
            for (int qq = 0; qq < 8; ++qq) {
                float e0 = FASTEXP(s0[2 * qq]), e1 = FASTEXP(s0[2 * qq + 1]);
                l_part += e0 + e1;
                pk[0][qq] = pack2bf_t(e0, e1);
                float f0 = FASTEXP(s1[2 * qq]), f1 = FASTEXP(s1[2 * qq + 1]);
                l_part += f0 + f1;
                pk[1][qq] = pack2bf_t(f0, f1);
            }
#pragma unroll
            for (int kc = 0; kc < 4; ++kc) {
                int ms = kc >> 1, Qb = 4 * (kc & 1);
                union { unsigned u[4]; bf16x8 v; } bu;
                bu.u[0] = pk[ms][Qb + 0];
                bu.u[1] = pk[ms][Qb + 1];
                bu.u[2] = pk[ms][Qb + 2];
                bu.u[3] = pk[ms][Qb + 3];
                bf16x8 av = *(const bf16x8*)&Vsb[vro[kc] + h * 64];
                accO = __builtin_amdgcn_mfma_f32_32x32x16_bf16(av, bu.v, accO, 0, 0, 0);
            }
        }
    }
    l_part += __shfl_xor(l_part, 32, 64);
    if (hf == 0) lp[((size_t)bh * HW + n_g) * 2 + mpart] = l_part;
    // epilogue: transpose O^T (C-layout) -> [n][d] in LDS, coalesced store
    __syncthreads();
    u16* tb = smem;                      // [128 n][32 d] pitch 36
    int nloc = wave * 32 + l31;
#pragma unroll
    for (int r = 0; r < 16; ++r) {
        int d = (r & 3) + 8 * (r >> 2) + 4 * hf;
        tb[nloc * 36 + d] = f2bf(accO[r]);
    }
    __syncthreads();
    size_t obase = ((size_t)(mpart * 16 + bh) * HW + blockIdx.x * 128) * 32;
#pragma unroll
    for (int i = 0; i < 2; ++i) {
        int row = i * 64 + (t >> 2), col = (t & 3) * 8;
        *(u16x8*)&Op[obase + (size_t)row * 32 + col] = *(const u16x8*)&tb[row * 36 + col];
    }
}

// ---------------- Output projection (fused combine) + bias + residual ----
// grid (128 p-tiles of 32, B) x 256. Coalesced Op[part][bh][n][32d] reads,
// 2-part fp32 sum, divide by summed l, LDS tile [p][c], MFMA GEMM.
__global__ __launch_bounds__(256) void proj_mfma_kernel(
    const u16* __restrict__ Op, const float* __restrict__ lp,
    const u16* __restrict__ wp, const float* __restrict__ proj_b,
    const float* __restrict__ x, float* __restrict__ out) {
    __shared__ u16 at_t[32 * 136];   // [p][c] pitch 136
    int b = blockIdx.y, p0 = blockIdx.x * 32, t = threadIdx.x;
#pragma unroll
    for (int i = 0; i < 2; ++i) {
        int u = t + 256 * i;                 // 512 units: p(32) x hh(4) x chunk(4)
        int p = u >> 4, hh = (u >> 2) & 3, ch = u & 3;
        int bh = b * NH + hh;
        size_t nidx = (size_t)bh * HW + p0 + p;
        float2 l2 = *(const float2*)&lp[nidx * 2];
        float lsum = l2.x + l2.y;
        float sum8[8] = {0.f,0.f,0.f,0.f,0.f,0.f,0.f,0.f};
#pragma unroll
        for (int part = 0; part < 2; ++part) {
            u16x8 ov = *(const u16x8*)&Op[((size_t)(part * 16 + bh) * HW + p0 + p) * 32 + ch * 8];
#pragma unroll
            for (int j = 0; j < 8; ++j) sum8[j] += bf2f(ov[j]);
        }
        float rin = RCPF(lsum);
#pragma unroll
        for (int j = 0; j < 8; ++j)
            at_t[p * 136 + (ch * 8 + j) * 4 + hh] = f2bf(sum8[j] * rin);
    }
    __syncthreads();
    int wave = t >> 6, lane = t & 63, l16 = lane & 15, quad = lane >> 4;
    f32x4 acc[2][2];
#pragma unroll
    for (int os = 0; os < 2; ++os)
#pragma unroll
        for (int ps = 0; ps < 2; ++ps) acc[os][ps] = f32x4{0.f, 0.f, 0.f, 0.f};
#pragma unroll
    for (int kc = 0; kc < 4; ++kc) {
        bf16x8 bfr[2];
#pragma unroll
        for (int ps = 0; ps < 2; ++ps)
            bfr[ps] = *(const bf16x8*)&at_t[(ps * 16 + l16) * 136 + kc * 32 + quad * 8];
#pragma unroll
        for (int os = 0; os < 2; ++os) {
            bf16x8 af = *(const bf16x8*)&wp[(size_t)(wave * 32 + os * 16 + l16) * 128 + kc * 32 + quad * 8];
#pragma unroll
            for (int ps = 0; ps < 2; ++ps)
                acc[os][ps] = __builtin_amdgcn_mfma_f32_16x16x32_bf16(af, bfr[ps], acc[os][ps], 0, 0, 0);
        }
    }
#pragma unroll
    for (int os = 0; os < 2; ++os) {
        int obase = wave * 32 + os * 16 + quad * 4;
#pragma unroll
        for (int ps = 0; ps < 2; ++ps) {
            int p = p0 + ps * 16 + l16;
#pragma unroll
            for (int r = 0; r < 4; ++r) {
                size_t idx = ((size_t)b * CH + obase + r) * HW + p;
                out[idx] = acc[os][ps][r] + proj_b[obase + r] + x[idx];
            }
        }
    }
}

extern "C" void kernel_launch(void* const* d_in, const int* in_sizes, int n_in,
                              void* d_out, int out_size, void* d_ws, size_t ws_size,
                              hipStream_t stream) {
    const float* x      = (const float*)d_in[0];
    const float* gn_w   = (const float*)d_in[1];
    const float* gn_b   = (const float*)d_in[2];
    const float* qkv_w  = (const float*)d_in[3];
    const float* qkv_b  = (const float*)d_in[4];
    const float* proj_w = (const float*)d_in[5];
    const float* proj_b = (const float*)d_in[6];
    float* out = (float*)d_out;

    char* W = (char*)d_ws;
    float* partials = (float*)(W + 0);                 // 4 KB
    u16*   wq       = (u16*)(W + 8192);                // 96 KB
    u16*   wp       = (u16*)(W + 8192 + 98304);        // 32 KB -> ends 139264
    u16*   qo       = (u16*)(W + 139264);              // 4 MB each
    u16*   ko       = qo + (size_t)2097152;
    u16*   vo       = ko + (size_t)2097152;
    u16*   Op       = vo + (size_t)2097152;            // 2 parts x 4 MB = 8 MB
    float* lp       = (float*)(Op + (size_t)2 * 2097152);  // 512 KB -> total ~25 MB

    hipLaunchKernelGGL(prep_kernel,      dim3(768),       dim3(256), 0, stream,
                       x, partials, qkv_w, proj_w, wq, wp);
    hipLaunchKernelGGL(qkv_mfma_kernel,  dim3(128, 4),    dim3(256), 0, stream,
                       x, gn_w, gn_b, wq, qkv_b, partials, qo, ko, vo);
    hipLaunchKernelGGL(attn_mfma_kernel, dim3(32, 2, 16), dim3(256), 0, stream,
                       qo, ko, vo, Op, lp);
    hipLaunchKernelGGL(proj_mfma_kernel, dim3(128, 4),    dim3(256), 0, stream,
                       Op, lp, wp, proj_b, x, out);
}